// Round 12
// baseline (3497.535 us; speedup 1.0000x reference)
//
#include <hip/hip_runtime.h>
#include <math.h>

#define VOCAB 50000
#define EMB 256
#define HID 512
#define KTAGS 20
#define START_TAG 18
#define END_TAG 19
#define BB 32
#define TT 256
#define NEGV -10000.0f
#define HSROW 644   // 512 phys + skew (4 per 16-float block)
#define XSROW 264   // 256 + 8 skew

__device__ __forceinline__ float sigmoidf_(float x) { return 1.0f / (1.0f + expf(-x)); }

// ---------------------------------------------------------------------------
// K2 r19: FINE-GRAINED WAVE-FLAG exchange on the r18 dir-split structure.
//   512 WGs x 512 thr (2/CU). WG = (dir, slice, grp). Cohort = (dir,grp).
//
//   r18 measured: 1665us, VALUBusy 35.6, Occ 25. Chain ~6.5us/step of which
//   ~4.2us wait. The wait is WG-coarse publication/observation: WG drain
//   barrier -> tid0 flag -> wave0 polls max-of-64 flags -> sync -> load.
//
//   r19 changes (chain attack, work unchanged):
//   - flags[cohort][slice] is a 64B line holding EIGHT per-wave words.
//     Producer wave w: gates -> wave-local s_waitcnt vmcnt(0) -> lane0
//     stores flags[slice][w]=t+1. No WG drain barrier; publication
//     de-skewed per wave.
//   - Consumer thread (kq,rA) depends on exactly ONE slice (kq>>1) and 4
//     waves ((kq&1)*4..+3): polls ONE dwordx4 of packed flags, then
//     immediately issues its 2 h-chunk loads. Observation de-skewed per
//     thread; poll->load hop overlaps across threads.
//   - Barriers 3 -> 2: [poll+load regs] SYNC [LDS write] SYNC [DOTRED,
//     gates, wave drain+flag, history].
//   Invariant (wave granularity): flag[s][w]>=t+1 implies that WG passed
//   its step-t staging barrier (all h(t) reads done) -> h(t+2) parity
//   writes can't race h(t) reads. Visibility: wave-local vmcnt(0) before
//   flag ensures flag>=t implies that wave's h(t) stores are in LLC.
// ---------------------------------------------------------------------------
__global__ __launch_bounds__(512, 4) void k_lstm_persist(
    const int* __restrict__ lengths,
    const int* __restrict__ sentence,  // [32][256]
    const float* __restrict__ emb,     // [VOCAB][256]
    const float* __restrict__ Wf_hh, const float* __restrict__ Wb_hh,
    const float* __restrict__ Wf_ih, const float* __restrict__ Wb_ih,
    const float* __restrict__ bf_ih, const float* __restrict__ bf_hh,
    const float* __restrict__ bb_ih, const float* __restrict__ bb_hh,
    float* __restrict__ hping,         // [2 parity][2 dir][32][512]
    unsigned* __restrict__ flags,      // [2 dir][4 grp][64 slice][16 uints: 8 wave words + pad]
    float* __restrict__ hbuf)          // [2][32][256][512]
{
    const int wg = blockIdx.x;             // 0..511
    const int dir = wg >> 8;               // 0=F, 1=B
    const int slice = (wg & 255) >> 2;     // unit slice 0..63
    const int grp = wg & 3;                // sorted batch group 0..3
    const int tid = threadIdx.x;
    const int wave = tid >> 6;             // 0..7 = local unit
    const int lane = tid & 63;             // k-slice
    const int u_glob = slice * 8 + wave;   // 0..511

    const float* Whh  = dir ? Wb_hh : Wf_hh;
    const float* WihP = dir ? Wb_ih : Wf_ih;
    const float* bihP = dir ? bb_ih : bf_ih;
    const float* bhhP = dir ? bb_hh : bf_hh;

    // recurrent weights: 8 h-floats per lane per gate (one dir only)
    float4 wD[4][2];
    #pragma unroll
    for (int c = 0; c < 4; c++) {
        const float4* wr = (const float4*)(Whh + (size_t)(c * HID + u_glob) * HID + lane * 8);
        wD[c][0] = wr[0]; wD[c][1] = wr[1];
    }
    // input weights: 4 x-floats per lane per gate
    float4 iD[4];
    #pragma unroll
    for (int c = 0; c < 4; c++)
        iD[c] = *(const float4*)(WihP + (size_t)(c * HID + u_glob) * EMB + lane * 4);
    // biases for this wave's unit
    float bc[4];
    #pragma unroll
    for (int c = 0; c < 4; c++)
        bc[c] = bihP[c * HID + u_glob] + bhhP[c * HID + u_glob];

    __shared__ float hs[8 * HSROW];        // 8 batch rows of h (this dir)
    __shared__ float xs[8 * XSROW];        // 8 batch rows of x (this dir)
    __shared__ float zw[8 * 132];          // [wave][gate*33 + j]
    __shared__ int stok[8][TT];            // tokens for group's 8 sorted batches
    __shared__ int lens_raw[32];
    __shared__ int order_s[32];
    __shared__ int lens_s[32];
    __shared__ int nbt_s[TT];

    if (tid < 32) lens_raw[tid] = lengths[tid];
    __syncthreads();
    if (tid < 32) {
        int me = lens_raw[tid], rank = 0;
        #pragma unroll 4
        for (int o = 0; o < 32; o++) {
            int lo = lens_raw[o];
            rank += (lo > me || (lo == me && o < tid)) ? 1 : 0;
        }
        order_s[rank] = tid;
        lens_s[rank] = me;
    }
    if (tid >= 256) {
        int t = tid - 256, c = 0;
        #pragma unroll 4
        for (int b = 0; b < 32; b++) c += (lens_raw[b] > t) ? 1 : 0;
        nbt_s[t] = c;
    }
    __syncthreads();
    for (int i = tid; i < 8 * TT; i += 512) {
        int j = i >> 8, c = i & 255;
        stok[j][c] = sentence[order_s[grp * 8 + j] * TT + c];
    }
    __syncthreads();

    const int tlimit = lens_s[grp * 8];

    // gate identity: lanes 0..7 = local sorted pos within group
    const int gj = lane & 7;
    const int g_act = (lane < 8);
    const int p_sort = grp * 8 + gj;
    const int mylen = lens_s[p_sort];
    const int mybat = order_s[p_sort];
    float* hout = hbuf + (size_t)(dir * BB + mybat) * TT * HID + u_glob;
    float* hp   = hping + (size_t)dir * BB * HID + (size_t)mybat * HID + u_glob; // parity-0 base

    // h staging: 2 slots/thread. kq = tid&127, rA = tid>>7 (0..3)
    const int kq = tid & 127;
    const int rA = tid >> 7;
    const int wbBase = 4 * kq + 4 * (kq >> 2);
    const int sb_lo = order_s[grp * 8 + rA];
    const int sb_hi = order_s[grp * 8 + rA + 4];
    const int sb0   = order_s[grp * 8];   // longest batch in group: always live
    const size_t o_lo = (size_t)sb_lo * 2048 + (size_t)kq * 16;
    const size_t o_hi = (size_t)sb_hi * 2048 + (size_t)kq * 16;
    const size_t o_fb = (size_t)sb0   * 2048 + (size_t)kq * 16;

    // x staging: row = wave (tid>>6), xpart = tid&63 (4 floats each)
    const int xrow = tid >> 6;
    const int xpart = tid & 63;
    const int xlen = lens_s[grp * 8 + xrow];
    float* xdst = &xs[xrow * XSROW + xpart * 4];

    const int rdoff = 8 * lane + 4 * (lane >> 1);

    float cS = 0.f;
    // producer: my slice's flag line; word = wave
    unsigned* myflagline = flags + ((size_t)(dir * 4 + grp) * 64 + slice) * 16;
    // consumer: my h-chunk (units kq*4..kq*4+3) = slice kq>>1, waves (kq&1)*4..+3
    const unsigned* pollq = flags + (size_t)(dir * 4 + grp) * 64 * 16
                          + (size_t)(kq >> 1) * 16 + (size_t)(kq & 1) * 4;

#define DOTRED()                                                               \
    for (int j = 0; j < jmax; j++) {                                           \
        const float* hb = &hs[j * HSROW + rdoff];                              \
        float4 h0 = *(const float4*)(hb);                                      \
        float4 h1 = *(const float4*)(hb + 4);                                  \
        float4 xv = *(const float4*)&xs[j * XSROW + lane * 4];                 \
        float a0 = 0.f, a1 = 0.f, a2 = 0.f, a3 = 0.f;                          \
        a0 = fmaf(wD[0][0].x, h0.x, a0); a0 = fmaf(wD[0][0].y, h0.y, a0);      \
        a0 = fmaf(wD[0][0].z, h0.z, a0); a0 = fmaf(wD[0][0].w, h0.w, a0);      \
        a0 = fmaf(wD[0][1].x, h1.x, a0); a0 = fmaf(wD[0][1].y, h1.y, a0);      \
        a0 = fmaf(wD[0][1].z, h1.z, a0); a0 = fmaf(wD[0][1].w, h1.w, a0);      \
        a0 = fmaf(iD[0].x, xv.x, a0);    a0 = fmaf(iD[0].y, xv.y, a0);         \
        a0 = fmaf(iD[0].z, xv.z, a0);    a0 = fmaf(iD[0].w, xv.w, a0);         \
        a1 = fmaf(wD[1][0].x, h0.x, a1); a1 = fmaf(wD[1][0].y, h0.y, a1);      \
        a1 = fmaf(wD[1][0].z, h0.z, a1); a1 = fmaf(wD[1][0].w, h0.w, a1);      \
        a1 = fmaf(wD[1][1].x, h1.x, a1); a1 = fmaf(wD[1][1].y, h1.y, a1);      \
        a1 = fmaf(wD[1][1].z, h1.z, a1); a1 = fmaf(wD[1][1].w, h1.w, a1);      \
        a1 = fmaf(iD[1].x, xv.x, a1);    a1 = fmaf(iD[1].y, xv.y, a1);         \
        a1 = fmaf(iD[1].z, xv.z, a1);    a1 = fmaf(iD[1].w, xv.w, a1);         \
        a2 = fmaf(wD[2][0].x, h0.x, a2); a2 = fmaf(wD[2][0].y, h0.y, a2);      \
        a2 = fmaf(wD[2][0].z, h0.z, a2); a2 = fmaf(wD[2][0].w, h0.w, a2);      \
        a2 = fmaf(wD[2][1].x, h1.x, a2); a2 = fmaf(wD[2][1].y, h1.y, a2);      \
        a2 = fmaf(wD[2][1].z, h1.z, a2); a2 = fmaf(wD[2][1].w, h1.w, a2);      \
        a2 = fmaf(iD[2].x, xv.x, a2);    a2 = fmaf(iD[2].y, xv.y, a2);         \
        a2 = fmaf(iD[2].z, xv.z, a2);    a2 = fmaf(iD[2].w, xv.w, a2);         \
        a3 = fmaf(wD[3][0].x, h0.x, a3); a3 = fmaf(wD[3][0].y, h0.y, a3);      \
        a3 = fmaf(wD[3][0].z, h0.z, a3); a3 = fmaf(wD[3][0].w, h0.w, a3);      \
        a3 = fmaf(wD[3][1].x, h1.x, a3); a3 = fmaf(wD[3][1].y, h1.y, a3);      \
        a3 = fmaf(wD[3][1].z, h1.z, a3); a3 = fmaf(wD[3][1].w, h1.w, a3);      \
        a3 = fmaf(iD[3].x, xv.x, a3);    a3 = fmaf(iD[3].y, xv.y, a3);         \
        a3 = fmaf(iD[3].z, xv.z, a3);    a3 = fmaf(iD[3].w, xv.w, a3);         \
        bool lo32 = (lane & 32) == 0;                                          \
        float tA = __shfl_xor(lo32 ? a2 : a0, 32);                             \
        float tB = __shfl_xor(lo32 ? a3 : a1, 32);                             \
        float rAq = (lo32 ? a0 : a2) + tA;                                     \
        float rBq = (lo32 ? a1 : a3) + tB;                                     \
        bool lo16 = (lane & 16) == 0;                                          \
        float tC = __shfl_xor(lo16 ? rBq : rAq, 16);                           \
        float r  = (lo16 ? rAq : rBq) + tC;                                    \
        r += __shfl_xor(r, 8);                                                 \
        r += __shfl_xor(r, 4);                                                 \
        r += __shfl_xor(r, 2);                                                 \
        r += __shfl_xor(r, 1);                                                 \
        if ((lane & 15) == 0)                                                  \
            zw[wave * 132 + (lane >> 4) * 33 + j] = r;                         \
    }

    for (int t = 0; t < tlimit; t++) {
        const int nbt = nbt_s[t];
        const int jmax = min(max(nbt - grp * 8, 0), 8);
        const int act = g_act && (t < mylen);
        const int pred_lo = (grp * 8 + rA < nbt);
        const int pred_hi = (grp * 8 + rA + 4 < nbt);

        // ---- prefetch x row (flag-independent) ----
        int posx = dir ? ((t < xlen) ? xlen - 1 - t : t) : t;
        const float* xr = emb + (size_t)stok[xrow][posx] * EMB + xpart * 4;
        float4 xa = *(const float4*)xr;

        // ---- per-thread poll: ONE dwordx4 of my 4 producer-wave flags ----
        if (t > 0) {
            const unsigned tgt = (unsigned)t;
            while (true) {
                uint4 f;
                asm volatile(
                    "global_load_dwordx4 %0, %1, off sc0 sc1\n\t"
                    "s_waitcnt vmcnt(0)"
                    : "=&v"(f) : "v"(pollq) : "memory");
                if (f.x >= tgt && f.y >= tgt && f.z >= tgt && f.w >= tgt) break;
                __builtin_amdgcn_s_sleep(2);
            }
        }

        // ---- load my h(t) chunks (immediately after MY producers ready) ----
        float4 u0, u1;
        {
            const char* baseD = (const char*)hping
                + ((size_t)(t & 1) * 2 * BB * HID + (size_t)dir * BB * HID) * 4;
            const char* fb = baseD + o_fb;
            const char* a0 = pred_lo ? baseD + o_lo : fb;
            const char* a1 = pred_hi ? baseD + o_hi : fb;
            asm volatile(
                "global_load_dwordx4 %0, %2, off sc0 sc1\n\t"
                "global_load_dwordx4 %1, %3, off sc0 sc1\n\t"
                "s_waitcnt vmcnt(0)"
                : "=&v"(u0), "=&v"(u1)
                : "v"(a0), "v"(a1)
                : "memory");
        }

        // ---- SYNC 1: all waves done with previous DOTRED's LDS reads ----
        __syncthreads();

        *(float4*)&hs[(rA    ) * HSROW + wbBase] = u0;
        *(float4*)&hs[(rA + 4) * HSROW + wbBase] = u1;
        *(float4*)xdst = xa;

        // ---- SYNC 2: staging visible to all waves ----
        __syncthreads();

        // ---- dot: Whh.h + Wih.x fused (one dir) ----
        DOTRED();

        // ---- gates; h-store; per-wave drain + per-wave flag ----
        float hn = 0.f;
        if (act) {
            float iv = zw[wave * 132 +  0 + gj] + bc[0];
            float fv = zw[wave * 132 + 33 + gj] + bc[1];
            float gv = zw[wave * 132 + 66 + gj] + bc[2];
            float ov = zw[wave * 132 + 99 + gj] + bc[3];
            float cn = sigmoidf_(fv) * cS + sigmoidf_(iv) * tanhf(gv);
            hn = sigmoidf_(ov) * tanhf(cn);
            cS = cn;
            __hip_atomic_store(hp + (size_t)(((t + 1) & 1) * 2) * BB * HID, hn,
                               __ATOMIC_RELAXED, __HIP_MEMORY_SCOPE_AGENT);
        }
        // wave-local drain of this wave's h stores, then publish this wave
        asm volatile("s_waitcnt vmcnt(0)" ::: "memory");
        if (t < tlimit - 1 && lane == 0)
            __hip_atomic_store(myflagline + wave, (unsigned)(t + 1),
                               __ATOMIC_RELAXED, __HIP_MEMORY_SCOPE_AGENT);

        // ---- history store AFTER flag (latency hides in next poll) ----
        if (act) hout[(size_t)t * HID] = hn;
    }
#undef DOTRED
}

// ---------------------------------------------------------------------------
// K3: feats — one wave per (b,t), all 64 lanes, LDS transpose-reduce.
// ---------------------------------------------------------------------------
__global__ __launch_bounds__(256) void k_feats(
    const int* __restrict__ lengths,
    const float* __restrict__ hbuf,  // [2][B][T][512]
    const float* __restrict__ Wout,  // [20][1024]
    const float* __restrict__ bout,  // [20]
    float* __restrict__ feats)       // [B][T][20]
{
    const int w = threadIdx.x >> 6;
    const int lane = threadIdx.x & 63;
    const int idx = blockIdx.x * 4 + w;
    const int b = idx >> 8, t = idx & 255;
    const int len = lengths[b];

    __shared__ float red[4][64][21];

    float acc[KTAGS];
    bool active = (t < len);
    if (active) {
        const int ofs = lane * 16;
        const float* src = (ofs < HID)
            ? hbuf + ((size_t)b * TT + t) * HID + ofs
            : hbuf + ((size_t)(BB + b) * TT + (len - 1 - t)) * HID + (ofs - HID);
        float x[16];
        #pragma unroll
        for (int q = 0; q < 4; q++) {
            float4 v = *(const float4*)(src + 4 * q);
            x[4 * q] = v.x; x[4 * q + 1] = v.y; x[4 * q + 2] = v.z; x[4 * q + 3] = v.w;
        }
        #pragma unroll
        for (int k = 0; k < KTAGS; k++) {
            const float* wr = Wout + (size_t)k * (2 * HID) + ofs;
            float a = 0.f;
            #pragma unroll
            for (int q = 0; q < 4; q++) {
                float4 v = *(const float4*)(wr + 4 * q);
                a = fmaf(x[4 * q], v.x, a);
                a = fmaf(x[4 * q + 1], v.y, a);
                a = fmaf(x[4 * q + 2], v.z, a);
                a = fmaf(x[4 * q + 3], v.w, a);
            }
            acc[k] = a;
        }
    } else {
        #pragma unroll
        for (int k = 0; k < KTAGS; k++) acc[k] = 0.f;
    }
    #pragma unroll
    for (int k = 0; k < KTAGS; k++) red[w][lane][k] = acc[k];
    __syncthreads();

    if (active && lane < KTAGS) {
        float s = bout[lane];
        #pragma unroll 8
        for (int l = 0; l < 64; l++) s += red[w][l][lane];
        feats[(size_t)idx * KTAGS + lane] = s;
    }
}

// ---------------------------------------------------------------------------
// K4: Viterbi — LDS backpointers, double-buffered fv, feats prefetch.
// ---------------------------------------------------------------------------
__global__ __launch_bounds__(64) void k_viterbi(
    const int* __restrict__ lengths,
    const float* __restrict__ trans,  // [20][20]
    const float* __restrict__ feats,  // [B][T][20]
    float* __restrict__ out)          // [32 scores][32*257 path]
{
    const int b = blockIdx.x;
    const int len = lengths[b];
    const int tid = threadIdx.x;

    __shared__ float tr[KTAGS * KTAGS];
    __shared__ float fvb[2][KTAGS];
    __shared__ int   bp[TT][KTAGS];
    __shared__ float term[KTAGS];

    for (int i = tid; i < KTAGS * KTAGS; i += 64) tr[i] = trans[i];
    if (tid < KTAGS) fvb[0][tid] = (tid == START_TAG) ? 0.f : NEGV;
    __syncthreads();

    float ft = (tid < KTAGS) ? feats[((size_t)b * TT) * KTAGS + tid] : 0.f;
    for (int t = 0; t < len; t++) {
        float ftn = (tid < KTAGS && t + 1 < len)
                  ? feats[((size_t)b * TT + t + 1) * KTAGS + tid] : 0.f;
        if (tid < KTAGS) {
            const float* fvc = fvb[t & 1];
            float best = -1e30f; int bi = 0;
            #pragma unroll
            for (int p = 0; p < KTAGS; p++) {
                float s = fvc[p] + tr[tid * KTAGS + p];
                if (s > best) { best = s; bi = p; }
            }
            fvb[(t + 1) & 1][tid] = best + ft;
            bp[t][tid] = bi;
        }
        ft = ftn;
        __syncthreads();
    }

    if (tid < KTAGS) term[tid] = fvb[len & 1][tid] + tr[END_TAG * KTAGS + tid];
    __syncthreads();

    if (tid == 0) {
        int bt_ = 0; float best = term[0];
        for (int k = 1; k < KTAGS; k++)
            if (term[k] > best) { best = term[k]; bt_ = k; }
        out[b] = best;
        float* path = out + BB + (size_t)b * (TT + 1);
        path[TT] = (float)bt_;
        int cur = bt_;
        for (int t = TT - 1; t >= 0; t--) {
            int src = t - (TT - len);
            if (src >= 0) cur = bp[src][cur];
            else          cur = KTAGS;
            path[t] = (float)cur;
        }
    }
}

// ---------------------------------------------------------------------------
extern "C" void kernel_launch(void* const* d_in, const int* in_sizes, int n_in,
                              void* d_out, int out_size, void* d_ws, size_t ws_size,
                              hipStream_t stream) {
    const int*   sentence = (const int*)d_in[0];
    const int*   lengths  = (const int*)d_in[1];
    const float* emb      = (const float*)d_in[2];
    const float* Wf_ih    = (const float*)d_in[3];
    const float* Wf_hh    = (const float*)d_in[4];
    const float* bf_ih    = (const float*)d_in[5];
    const float* bf_hh    = (const float*)d_in[6];
    const float* Wb_ih    = (const float*)d_in[7];
    const float* Wb_hh    = (const float*)d_in[8];
    const float* bb_ih    = (const float*)d_in[9];
    const float* bb_hh    = (const float*)d_in[10];
    const float* Wout     = (const float*)d_in[11];
    const float* bout     = (const float*)d_in[12];
    const float* trans    = (const float*)d_in[13];
    float* out = (float*)d_out;

    // workspace layout
    float*    hping = (float*)d_ws;                              // 65536 floats (256KB)
    unsigned* flags = (unsigned*)((char*)d_ws + 262144);         // 32KB (512 x 64B lines)
    float*    hbuf  = (float*)((char*)d_ws + 262144 + 32768);    // 2*32*256*512 floats
    float*    feats = hbuf + (size_t)2 * BB * TT * HID;          // 32*256*20

    (void)hipMemsetAsync(d_ws, 0, 262144 + 32768, stream);

    hipLaunchKernelGGL(k_lstm_persist, dim3(512), dim3(512), 0, stream,
                       lengths, sentence, emb, Wf_hh, Wb_hh, Wf_ih, Wb_ih,
                       bf_ih, bf_hh, bb_ih, bb_hh, hping, flags, hbuf);
    hipLaunchKernelGGL(k_feats, dim3(BB * TT / 4), dim3(256), 0, stream,
                       lengths, hbuf, Wout, bout, feats);
    hipLaunchKernelGGL(k_viterbi, dim3(BB), dim3(64), 0, stream,
                       lengths, trans, feats, out);
}

// Round 13
// 3265.782 us; speedup vs baseline: 1.0710x; 1.0710x over previous
//
#include <hip/hip_runtime.h>
#include <math.h>

#define VOCAB 50000
#define EMB 256
#define HID 512
#define KTAGS 20
#define START_TAG 18
#define END_TAG 19
#define BB 32
#define TT 256
#define NEGV -10000.0f
#define HSROW 644   // 512 phys + skew (4 per 16-float block)
#define XSROW 264   // 256 + 8 skew

__device__ __forceinline__ float sigmoidf_(float x) { return 1.0f / (1.0f + expf(-x)); }

// ---------------------------------------------------------------------------
// K2 r20: r18 protocol (wave0-poll + flag lines, known 1665us) + two
// critical-path cuts. r19's per-thread poll REGRESSED (3379us): divergent
// poll loops execute at WAVE granularity, so observation was never
// per-thread; it just multiplied pollers 8x. Protocol stays r18-shaped.
//
//   r20 changes (work schedule, not protocol):
//   - zx HOIST: x(t) is known in advance; stage x one step ahead and
//     compute zx[j] = Wih.x(t) partials at the TOP of step t (before
//     SYNC1). Waves 1-7 do this while wave0 polls; DOTRED's
//     barrier-serialized body shrinks 48->32 fmaf/j, zx folded in as
//     accumulator init (no extra reduce).
//   - LDS ARRIVAL COUNT replaces barrier #3: each wave drains its own
//     h-stores (vmcnt(0)), lane0 atomicAdd(lds_cnt); the 8th arriver
//     (old==t*8+7) publishes flag=t+1 immediately. Publication at
//     last-wave-drain, not after barrier+reconverge. 2 barriers/step.
//   Invariant unchanged: flag==t+1 => WG passed staging(t) (all parity
//   reads done) => h(t+2) writes can't race h(t) reads. Each wave
//   increments only after its own drain => publish => all h in LLC.
// ---------------------------------------------------------------------------
__global__ __launch_bounds__(512, 4) void k_lstm_persist(
    const int* __restrict__ lengths,
    const int* __restrict__ sentence,  // [32][256]
    const float* __restrict__ emb,     // [VOCAB][256]
    const float* __restrict__ Wf_hh, const float* __restrict__ Wb_hh,
    const float* __restrict__ Wf_ih, const float* __restrict__ Wb_ih,
    const float* __restrict__ bf_ih, const float* __restrict__ bf_hh,
    const float* __restrict__ bb_ih, const float* __restrict__ bb_hh,
    float* __restrict__ hping,         // [2 parity][2 dir][32][512]
    unsigned* __restrict__ flags,      // [2 dir][4 grp][64 slice][16 uints]
    float* __restrict__ hbuf)          // [2][32][256][512]
{
    const int wg = blockIdx.x;             // 0..511
    const int dir = wg >> 8;               // 0=F, 1=B
    const int slice = (wg & 255) >> 2;     // unit slice 0..63
    const int grp = wg & 3;                // sorted batch group 0..3
    const int tid = threadIdx.x;
    const int wave = tid >> 6;             // 0..7 = local unit
    const int lane = tid & 63;             // k-slice
    const int u_glob = slice * 8 + wave;   // 0..511

    const float* Whh  = dir ? Wb_hh : Wf_hh;
    const float* WihP = dir ? Wb_ih : Wf_ih;
    const float* bihP = dir ? bb_ih : bf_ih;
    const float* bhhP = dir ? bb_hh : bf_hh;

    // recurrent weights: 8 h-floats per lane per gate (one dir only)
    float4 wD[4][2];
    #pragma unroll
    for (int c = 0; c < 4; c++) {
        const float4* wr = (const float4*)(Whh + (size_t)(c * HID + u_glob) * HID + lane * 8);
        wD[c][0] = wr[0]; wD[c][1] = wr[1];
    }
    // input weights: 4 x-floats per lane per gate
    float4 iD[4];
    #pragma unroll
    for (int c = 0; c < 4; c++)
        iD[c] = *(const float4*)(WihP + (size_t)(c * HID + u_glob) * EMB + lane * 4);
    // biases for this wave's unit
    float bc[4];
    #pragma unroll
    for (int c = 0; c < 4; c++)
        bc[c] = bihP[c * HID + u_glob] + bhhP[c * HID + u_glob];

    __shared__ float hs[8 * HSROW];        // 8 batch rows of h (this dir)
    __shared__ float xs[8 * XSROW];        // 8 batch rows of x (this dir), 1-step-ahead
    __shared__ float zw[8 * 132];          // [wave][gate*33 + j]
    __shared__ int stok[8][TT];            // tokens for group's 8 sorted batches
    __shared__ int lens_raw[32];
    __shared__ int order_s[32];
    __shared__ int lens_s[32];
    __shared__ int nbt_s[TT];
    __shared__ unsigned lds_cnt;           // monotonic wave-arrival counter

    if (tid < 32) lens_raw[tid] = lengths[tid];
    if (tid == 33) lds_cnt = 0u;
    __syncthreads();
    if (tid < 32) {
        int me = lens_raw[tid], rank = 0;
        #pragma unroll 4
        for (int o = 0; o < 32; o++) {
            int lo = lens_raw[o];
            rank += (lo > me || (lo == me && o < tid)) ? 1 : 0;
        }
        order_s[rank] = tid;
        lens_s[rank] = me;
    }
    if (tid >= 256) {
        int t = tid - 256, c = 0;
        #pragma unroll 4
        for (int b = 0; b < 32; b++) c += (lens_raw[b] > t) ? 1 : 0;
        nbt_s[t] = c;
    }
    __syncthreads();
    for (int i = tid; i < 8 * TT; i += 512) {
        int j = i >> 8, c = i & 255;
        stok[j][c] = sentence[order_s[grp * 8 + j] * TT + c];
    }
    __syncthreads();

    const int tlimit = lens_s[grp * 8];

    // gate identity: lanes 0..7 = local sorted pos within group
    const int gj = lane & 7;
    const int g_act = (lane < 8);
    const int p_sort = grp * 8 + gj;
    const int mylen = lens_s[p_sort];
    const int mybat = order_s[p_sort];
    float* hout = hbuf + (size_t)(dir * BB + mybat) * TT * HID + u_glob;
    float* hp   = hping + (size_t)dir * BB * HID + (size_t)mybat * HID + u_glob; // parity-0 base

    // h staging: 2 slots/thread. kq = tid&127, rA = tid>>7 (0..3)
    const int kq = tid & 127;
    const int rA = tid >> 7;
    const int wbBase = 4 * kq + 4 * (kq >> 2);
    const int sb_lo = order_s[grp * 8 + rA];
    const int sb_hi = order_s[grp * 8 + rA + 4];
    const int sb0   = order_s[grp * 8];   // longest batch in group: always live
    const size_t o_lo = (size_t)sb_lo * 2048 + (size_t)kq * 16;
    const size_t o_hi = (size_t)sb_hi * 2048 + (size_t)kq * 16;
    const size_t o_fb = (size_t)sb0   * 2048 + (size_t)kq * 16;

    // x staging: row = wave (tid>>6), xpart = tid&63 (4 floats each)
    const int xrow = tid >> 6;
    const int xpart = tid & 63;
    const int xlen = lens_s[grp * 8 + xrow];
    float* xdst = &xs[xrow * XSROW + xpart * 4];

    const int rdoff = 8 * lane + 4 * (lane >> 1);

    float cS = 0.f;
    unsigned* myflag = flags + ((size_t)(dir * 4 + grp) * 64 + slice) * 16;
    const unsigned* pollbase = flags + (size_t)(dir * 4 + grp) * 64 * 16;

    // ---- prologue: stage x(0) into xs (consumed by zx at t=0) ----
    {
        int posx = dir ? (xlen - 1) : 0;   // xlen >= 1 always
        const float* xr = emb + (size_t)stok[xrow][posx] * EMB + xpart * 4;
        *(float4*)xdst = *(const float4*)xr;
    }
    __syncthreads();

    for (int t = 0; t < tlimit; t++) {
        const int nbt = nbt_s[t];
        const int jmax = min(max(nbt - grp * 8, 0), 8);
        const int act = g_act && (t < mylen);
        const int pred_lo = (grp * 8 + rA < nbt);
        const int pred_hi = (grp * 8 + rA + 4 < nbt);

        // ---- issue x(t+1) prefetch (consumed at staging below) ----
        float4 xa;
        {
            int tp = (t + 1 < tlimit) ? t + 1 : t;
            int posn = dir ? ((tp < xlen) ? xlen - 1 - tp : tp) : tp;
            const float* xrn = emb + (size_t)stok[xrow][posn] * EMB + xpart * 4;
            xa = *(const float4*)xrn;
        }

        // ---- zx hoist: Wih.x(t) partials, all waves, off critical path ----
        float4 zxp[8];
        #pragma unroll
        for (int j = 0; j < 8; j++) {
            float4 xv = *(const float4*)&xs[j * XSROW + lane * 4];
            float4 p;
            p.x = iD[0].x * xv.x; p.x = fmaf(iD[0].y, xv.y, p.x);
            p.x = fmaf(iD[0].z, xv.z, p.x); p.x = fmaf(iD[0].w, xv.w, p.x);
            p.y = iD[1].x * xv.x; p.y = fmaf(iD[1].y, xv.y, p.y);
            p.y = fmaf(iD[1].z, xv.z, p.y); p.y = fmaf(iD[1].w, xv.w, p.y);
            p.z = iD[2].x * xv.x; p.z = fmaf(iD[2].y, xv.y, p.z);
            p.z = fmaf(iD[2].z, xv.z, p.z); p.z = fmaf(iD[2].w, xv.w, p.z);
            p.w = iD[3].x * xv.x; p.w = fmaf(iD[3].y, xv.y, p.w);
            p.w = fmaf(iD[3].z, xv.z, p.w); p.w = fmaf(iD[3].w, xv.w, p.w);
            zxp[j] = p;
        }

        // ---- flag wait: wave0 only; lane l watches slice l's flag line ----
        if (t > 0 && wave == 0) {
            const unsigned tgt = (unsigned)t;
            const unsigned* cp = pollbase + lane * 16;
            bool mydone = false;
            while (true) {
                if (!mydone)
                    mydone = __hip_atomic_load(cp, __ATOMIC_RELAXED,
                                               __HIP_MEMORY_SCOPE_AGENT) >= tgt;
                if (__ballot(mydone) == ~0ull) break;
                __builtin_amdgcn_s_sleep(1);
            }
        }
        __syncthreads();   // SYNC1: zx reads of xs done; cohort h(t) published

        // ---- stage h(t): 2 sc1 dwordx4 loads, one vmcnt; write x(t+1) ----
        {
            const char* baseD = (const char*)hping
                + ((size_t)(t & 1) * 2 * BB * HID + (size_t)dir * BB * HID) * 4;
            const char* fb = baseD + o_fb;
            const char* a0 = pred_lo ? baseD + o_lo : fb;
            const char* a1 = pred_hi ? baseD + o_hi : fb;
            float4 u0, u1;
            asm volatile(
                "global_load_dwordx4 %0, %2, off sc0 sc1\n\t"
                "global_load_dwordx4 %1, %3, off sc0 sc1\n\t"
                "s_waitcnt vmcnt(0)"
                : "=&v"(u0), "=&v"(u1)
                : "v"(a0), "v"(a1)
                : "memory");
            *(float4*)&hs[(rA    ) * HSROW + wbBase] = u0;
            *(float4*)&hs[(rA + 4) * HSROW + wbBase] = u1;
            *(float4*)xdst = xa;
        }
        __syncthreads();   // SYNC2: staging visible

        // ---- dot: Whh.h only (zx folded in as accumulator init) ----
        for (int j = 0; j < jmax; j++) {
            const float* hb = &hs[j * HSROW + rdoff];
            float4 h0 = *(const float4*)(hb);
            float4 h1 = *(const float4*)(hb + 4);
            float a0 = zxp[j].x, a1 = zxp[j].y, a2 = zxp[j].z, a3 = zxp[j].w;
            a0 = fmaf(wD[0][0].x, h0.x, a0); a0 = fmaf(wD[0][0].y, h0.y, a0);
            a0 = fmaf(wD[0][0].z, h0.z, a0); a0 = fmaf(wD[0][0].w, h0.w, a0);
            a0 = fmaf(wD[0][1].x, h1.x, a0); a0 = fmaf(wD[0][1].y, h1.y, a0);
            a0 = fmaf(wD[0][1].z, h1.z, a0); a0 = fmaf(wD[0][1].w, h1.w, a0);
            a1 = fmaf(wD[1][0].x, h0.x, a1); a1 = fmaf(wD[1][0].y, h0.y, a1);
            a1 = fmaf(wD[1][0].z, h0.z, a1); a1 = fmaf(wD[1][0].w, h0.w, a1);
            a1 = fmaf(wD[1][1].x, h1.x, a1); a1 = fmaf(wD[1][1].y, h1.y, a1);
            a1 = fmaf(wD[1][1].z, h1.z, a1); a1 = fmaf(wD[1][1].w, h1.w, a1);
            a2 = fmaf(wD[2][0].x, h0.x, a2); a2 = fmaf(wD[2][0].y, h0.y, a2);
            a2 = fmaf(wD[2][0].z, h0.z, a2); a2 = fmaf(wD[2][0].w, h0.w, a2);
            a2 = fmaf(wD[2][1].x, h1.x, a2); a2 = fmaf(wD[2][1].y, h1.y, a2);
            a2 = fmaf(wD[2][1].z, h1.z, a2); a2 = fmaf(wD[2][1].w, h1.w, a2);
            a3 = fmaf(wD[3][0].x, h0.x, a3); a3 = fmaf(wD[3][0].y, h0.y, a3);
            a3 = fmaf(wD[3][0].z, h0.z, a3); a3 = fmaf(wD[3][0].w, h0.w, a3);
            a3 = fmaf(wD[3][1].x, h1.x, a3); a3 = fmaf(wD[3][1].y, h1.y, a3);
            a3 = fmaf(wD[3][1].z, h1.z, a3); a3 = fmaf(wD[3][1].w, h1.w, a3);
            bool lo32 = (lane & 32) == 0;
            float tA = __shfl_xor(lo32 ? a2 : a0, 32);
            float tB = __shfl_xor(lo32 ? a3 : a1, 32);
            float rAq = (lo32 ? a0 : a2) + tA;
            float rBq = (lo32 ? a1 : a3) + tB;
            bool lo16 = (lane & 16) == 0;
            float tC = __shfl_xor(lo16 ? rBq : rAq, 16);
            float r  = (lo16 ? rAq : rBq) + tC;
            r += __shfl_xor(r, 8);
            r += __shfl_xor(r, 4);
            r += __shfl_xor(r, 2);
            r += __shfl_xor(r, 1);
            if ((lane & 15) == 0)
                zw[wave * 132 + (lane >> 4) * 33 + j] = r;
        }

        // ---- gates (read own wave's zw, no barrier needed); h-store ----
        float hn = 0.f;
        if (act) {
            float iv = zw[wave * 132 +  0 + gj] + bc[0];
            float fv = zw[wave * 132 + 33 + gj] + bc[1];
            float gv = zw[wave * 132 + 66 + gj] + bc[2];
            float ov = zw[wave * 132 + 99 + gj] + bc[3];
            float cn = sigmoidf_(fv) * cS + sigmoidf_(iv) * tanhf(gv);
            hn = sigmoidf_(ov) * tanhf(cn);
            cS = cn;
            __hip_atomic_store(hp + (size_t)(((t + 1) & 1) * 2) * BB * HID, hn,
                               __ATOMIC_RELAXED, __HIP_MEMORY_SCOPE_AGENT);
        }

        // ---- per-wave drain + LDS arrival; 8th arriver publishes flag ----
        asm volatile("s_waitcnt vmcnt(0)" ::: "memory");
        if (lane == 0) {
            unsigned old = atomicAdd(&lds_cnt, 1u);
            if (old == (unsigned)(t * 8 + 7) && t < tlimit - 1)
                __hip_atomic_store(myflag, (unsigned)(t + 1),
                                   __ATOMIC_RELAXED, __HIP_MEMORY_SCOPE_AGENT);
        }

        // ---- history store AFTER arrive (latency hides in next phase) ----
        if (act) hout[(size_t)t * HID] = hn;
    }
}

// ---------------------------------------------------------------------------
// K3: feats — one wave per (b,t), all 64 lanes, LDS transpose-reduce.
// ---------------------------------------------------------------------------
__global__ __launch_bounds__(256) void k_feats(
    const int* __restrict__ lengths,
    const float* __restrict__ hbuf,  // [2][B][T][512]
    const float* __restrict__ Wout,  // [20][1024]
    const float* __restrict__ bout,  // [20]
    float* __restrict__ feats)       // [B][T][20]
{
    const int w = threadIdx.x >> 6;
    const int lane = threadIdx.x & 63;
    const int idx = blockIdx.x * 4 + w;
    const int b = idx >> 8, t = idx & 255;
    const int len = lengths[b];

    __shared__ float red[4][64][21];

    float acc[KTAGS];
    bool active = (t < len);
    if (active) {
        const int ofs = lane * 16;
        const float* src = (ofs < HID)
            ? hbuf + ((size_t)b * TT + t) * HID + ofs
            : hbuf + ((size_t)(BB + b) * TT + (len - 1 - t)) * HID + (ofs - HID);
        float x[16];
        #pragma unroll
        for (int q = 0; q < 4; q++) {
            float4 v = *(const float4*)(src + 4 * q);
            x[4 * q] = v.x; x[4 * q + 1] = v.y; x[4 * q + 2] = v.z; x[4 * q + 3] = v.w;
        }
        #pragma unroll
        for (int k = 0; k < KTAGS; k++) {
            const float* wr = Wout + (size_t)k * (2 * HID) + ofs;
            float a = 0.f;
            #pragma unroll
            for (int q = 0; q < 4; q++) {
                float4 v = *(const float4*)(wr + 4 * q);
                a = fmaf(x[4 * q], v.x, a);
                a = fmaf(x[4 * q + 1], v.y, a);
                a = fmaf(x[4 * q + 2], v.z, a);
                a = fmaf(x[4 * q + 3], v.w, a);
            }
            acc[k] = a;
        }
    } else {
        #pragma unroll
        for (int k = 0; k < KTAGS; k++) acc[k] = 0.f;
    }
    #pragma unroll
    for (int k = 0; k < KTAGS; k++) red[w][lane][k] = acc[k];
    __syncthreads();

    if (active && lane < KTAGS) {
        float s = bout[lane];
        #pragma unroll 8
        for (int l = 0; l < 64; l++) s += red[w][l][lane];
        feats[(size_t)idx * KTAGS + lane] = s;
    }
}

// ---------------------------------------------------------------------------
// K4: Viterbi — LDS backpointers, double-buffered fv, feats prefetch.
// ---------------------------------------------------------------------------
__global__ __launch_bounds__(64) void k_viterbi(
    const int* __restrict__ lengths,
    const float* __restrict__ trans,  // [20][20]
    const float* __restrict__ feats,  // [B][T][20]
    float* __restrict__ out)          // [32 scores][32*257 path]
{
    const int b = blockIdx.x;
    const int len = lengths[b];
    const int tid = threadIdx.x;

    __shared__ float tr[KTAGS * KTAGS];
    __shared__ float fvb[2][KTAGS];
    __shared__ int   bp[TT][KTAGS];
    __shared__ float term[KTAGS];

    for (int i = tid; i < KTAGS * KTAGS; i += 64) tr[i] = trans[i];
    if (tid < KTAGS) fvb[0][tid] = (tid == START_TAG) ? 0.f : NEGV;
    __syncthreads();

    float ft = (tid < KTAGS) ? feats[((size_t)b * TT) * KTAGS + tid] : 0.f;
    for (int t = 0; t < len; t++) {
        float ftn = (tid < KTAGS && t + 1 < len)
                  ? feats[((size_t)b * TT + t + 1) * KTAGS + tid] : 0.f;
        if (tid < KTAGS) {
            const float* fvc = fvb[t & 1];
            float best = -1e30f; int bi = 0;
            #pragma unroll
            for (int p = 0; p < KTAGS; p++) {
                float s = fvc[p] + tr[tid * KTAGS + p];
                if (s > best) { best = s; bi = p; }
            }
            fvb[(t + 1) & 1][tid] = best + ft;
            bp[t][tid] = bi;
        }
        ft = ftn;
        __syncthreads();
    }

    if (tid < KTAGS) term[tid] = fvb[len & 1][tid] + tr[END_TAG * KTAGS + tid];
    __syncthreads();

    if (tid == 0) {
        int bt_ = 0; float best = term[0];
        for (int k = 1; k < KTAGS; k++)
            if (term[k] > best) { best = term[k]; bt_ = k; }
        out[b] = best;
        float* path = out + BB + (size_t)b * (TT + 1);
        path[TT] = (float)bt_;
        int cur = bt_;
        for (int t = TT - 1; t >= 0; t--) {
            int src = t - (TT - len);
            if (src >= 0) cur = bp[src][cur];
            else          cur = KTAGS;
            path[t] = (float)cur;
        }
    }
}

// ---------------------------------------------------------------------------
extern "C" void kernel_launch(void* const* d_in, const int* in_sizes, int n_in,
                              void* d_out, int out_size, void* d_ws, size_t ws_size,
                              hipStream_t stream) {
    const int*   sentence = (const int*)d_in[0];
    const int*   lengths  = (const int*)d_in[1];
    const float* emb      = (const float*)d_in[2];
    const float* Wf_ih    = (const float*)d_in[3];
    const float* Wf_hh    = (const float*)d_in[4];
    const float* bf_ih    = (const float*)d_in[5];
    const float* bf_hh    = (const float*)d_in[6];
    const float* Wb_ih    = (const float*)d_in[7];
    const float* Wb_hh    = (const float*)d_in[8];
    const float* bb_ih    = (const float*)d_in[9];
    const float* bb_hh    = (const float*)d_in[10];
    const float* Wout     = (const float*)d_in[11];
    const float* bout     = (const float*)d_in[12];
    const float* trans    = (const float*)d_in[13];
    float* out = (float*)d_out;

    // workspace layout
    float*    hping = (float*)d_ws;                              // 65536 floats (256KB)
    unsigned* flags = (unsigned*)((char*)d_ws + 262144);         // 32KB (512 x 64B lines)
    float*    hbuf  = (float*)((char*)d_ws + 262144 + 32768);    // 2*32*256*512 floats
    float*    feats = hbuf + (size_t)2 * BB * TT * HID;          // 32*256*20

    (void)hipMemsetAsync(d_ws, 0, 262144 + 32768, stream);

    hipLaunchKernelGGL(k_lstm_persist, dim3(512), dim3(512), 0, stream,
                       lengths, sentence, emb, Wf_hh, Wb_hh, Wf_ih, Wb_ih,
                       bf_ih, bf_hh, bb_ih, bb_hh, hping, flags, hbuf);
    hipLaunchKernelGGL(k_feats, dim3(BB * TT / 4), dim3(256), 0, stream,
                       lengths, hbuf, Wout, bout, feats);
    hipLaunchKernelGGL(k_viterbi, dim3(BB), dim3(64), 0, stream,
                       lengths, trans, feats, out);
}

// Round 14
// 2172.052 us; speedup vs baseline: 1.6102x; 1.5035x over previous
//
#include <hip/hip_runtime.h>
#include <math.h>

#define VOCAB 50000
#define EMB 256
#define HID 512
#define KTAGS 20
#define START_TAG 18
#define END_TAG 19
#define BB 32
#define TT 256
#define NEGV -10000.0f
#define HSROW 644   // 512 phys + skew (4 per 16-float block)
#define XSROW 264   // 256 + 8 skew

__device__ __forceinline__ float sigmoidf_(float x) { return 1.0f / (1.0f + expf(-x)); }

// ---------------------------------------------------------------------------
// K2 r21: r20 structure with the SCRATCH-SPILL FIX.
//   r20 measured 3130us with VGPR=56, FETCH 645MB, WRITE 4.6GB: DOTRED's
//   runtime-bound loop `for (j<jmax)` indexed zxp[j] with runtime j ->
//   compiler allocated zxp in SCRATCH (guide rule #20). ~5GB/dispatch of
//   scratch traffic, LLC thrash, VALUBusy 18. The r20 schedule itself was
//   never really tested.
//   r21: DOTRED fully unrolled over constant 8 with wave-uniform
//   `if (j < jmax)` guard -> all zxp indices compile-time -> registers.
//   Everything else identical to r20:
//   - r18 protocol (wave0-poll + per-WG flag lines) - known good.
//   - zx HOIST: Wih.x(t) partials computed at top of step (off the
//     barrier-serialized path; overlaps wave0's poll); DOTRED body
//     48->32 fmaf/j with zx as accumulator init.
//   - LDS ARRIVAL COUNT replaces drain barrier: per-wave vmcnt(0) then
//     lane0 atomicAdd; 8th arriver (old==t*8+7) publishes flag=t+1.
//     2 barriers/step. Invariants: flag==t+1 => WG passed staging(t)
//     => h(t+2) parity writes can't race h(t) reads; publish-after-
//     all-drains => flag implies h in LLC.
// ---------------------------------------------------------------------------
__global__ __launch_bounds__(512, 4) void k_lstm_persist(
    const int* __restrict__ lengths,
    const int* __restrict__ sentence,  // [32][256]
    const float* __restrict__ emb,     // [VOCAB][256]
    const float* __restrict__ Wf_hh, const float* __restrict__ Wb_hh,
    const float* __restrict__ Wf_ih, const float* __restrict__ Wb_ih,
    const float* __restrict__ bf_ih, const float* __restrict__ bf_hh,
    const float* __restrict__ bb_ih, const float* __restrict__ bb_hh,
    float* __restrict__ hping,         // [2 parity][2 dir][32][512]
    unsigned* __restrict__ flags,      // [2 dir][4 grp][64 slice][16 uints]
    float* __restrict__ hbuf)          // [2][32][256][512]
{
    const int wg = blockIdx.x;             // 0..511
    const int dir = wg >> 8;               // 0=F, 1=B
    const int slice = (wg & 255) >> 2;     // unit slice 0..63
    const int grp = wg & 3;                // sorted batch group 0..3
    const int tid = threadIdx.x;
    const int wave = tid >> 6;             // 0..7 = local unit
    const int lane = tid & 63;             // k-slice
    const int u_glob = slice * 8 + wave;   // 0..511

    const float* Whh  = dir ? Wb_hh : Wf_hh;
    const float* WihP = dir ? Wb_ih : Wf_ih;
    const float* bihP = dir ? bb_ih : bf_ih;
    const float* bhhP = dir ? bb_hh : bf_hh;

    // recurrent weights: 8 h-floats per lane per gate (one dir only)
    float4 wD[4][2];
    #pragma unroll
    for (int c = 0; c < 4; c++) {
        const float4* wr = (const float4*)(Whh + (size_t)(c * HID + u_glob) * HID + lane * 8);
        wD[c][0] = wr[0]; wD[c][1] = wr[1];
    }
    // input weights: 4 x-floats per lane per gate
    float4 iD[4];
    #pragma unroll
    for (int c = 0; c < 4; c++)
        iD[c] = *(const float4*)(WihP + (size_t)(c * HID + u_glob) * EMB + lane * 4);
    // biases for this wave's unit
    float bc[4];
    #pragma unroll
    for (int c = 0; c < 4; c++)
        bc[c] = bihP[c * HID + u_glob] + bhhP[c * HID + u_glob];

    __shared__ float hs[8 * HSROW];        // 8 batch rows of h (this dir)
    __shared__ float xs[8 * XSROW];        // 8 batch rows of x (this dir), 1-step-ahead
    __shared__ float zw[8 * 132];          // [wave][gate*33 + j]
    __shared__ int stok[8][TT];            // tokens for group's 8 sorted batches
    __shared__ int lens_raw[32];
    __shared__ int order_s[32];
    __shared__ int lens_s[32];
    __shared__ int nbt_s[TT];
    __shared__ unsigned lds_cnt;           // monotonic wave-arrival counter

    if (tid < 32) lens_raw[tid] = lengths[tid];
    if (tid == 33) lds_cnt = 0u;
    __syncthreads();
    if (tid < 32) {
        int me = lens_raw[tid], rank = 0;
        #pragma unroll 4
        for (int o = 0; o < 32; o++) {
            int lo = lens_raw[o];
            rank += (lo > me || (lo == me && o < tid)) ? 1 : 0;
        }
        order_s[rank] = tid;
        lens_s[rank] = me;
    }
    if (tid >= 256) {
        int t = tid - 256, c = 0;
        #pragma unroll 4
        for (int b = 0; b < 32; b++) c += (lens_raw[b] > t) ? 1 : 0;
        nbt_s[t] = c;
    }
    __syncthreads();
    for (int i = tid; i < 8 * TT; i += 512) {
        int j = i >> 8, c = i & 255;
        stok[j][c] = sentence[order_s[grp * 8 + j] * TT + c];
    }
    __syncthreads();

    const int tlimit = lens_s[grp * 8];

    // gate identity: lanes 0..7 = local sorted pos within group
    const int gj = lane & 7;
    const int g_act = (lane < 8);
    const int p_sort = grp * 8 + gj;
    const int mylen = lens_s[p_sort];
    const int mybat = order_s[p_sort];
    float* hout = hbuf + (size_t)(dir * BB + mybat) * TT * HID + u_glob;
    float* hp   = hping + (size_t)dir * BB * HID + (size_t)mybat * HID + u_glob; // parity-0 base

    // h staging: 2 slots/thread. kq = tid&127, rA = tid>>7 (0..3)
    const int kq = tid & 127;
    const int rA = tid >> 7;
    const int wbBase = 4 * kq + 4 * (kq >> 2);
    const int sb_lo = order_s[grp * 8 + rA];
    const int sb_hi = order_s[grp * 8 + rA + 4];
    const int sb0   = order_s[grp * 8];   // longest batch in group: always live
    const size_t o_lo = (size_t)sb_lo * 2048 + (size_t)kq * 16;
    const size_t o_hi = (size_t)sb_hi * 2048 + (size_t)kq * 16;
    const size_t o_fb = (size_t)sb0   * 2048 + (size_t)kq * 16;

    // x staging: row = wave (tid>>6), xpart = tid&63 (4 floats each)
    const int xrow = tid >> 6;
    const int xpart = tid & 63;
    const int xlen = lens_s[grp * 8 + xrow];
    float* xdst = &xs[xrow * XSROW + xpart * 4];

    const int rdoff = 8 * lane + 4 * (lane >> 1);

    float cS = 0.f;
    unsigned* myflag = flags + ((size_t)(dir * 4 + grp) * 64 + slice) * 16;
    const unsigned* pollbase = flags + (size_t)(dir * 4 + grp) * 64 * 16;

    // ---- prologue: stage x(0) into xs (consumed by zx at t=0) ----
    {
        int posx = dir ? (xlen - 1) : 0;   // xlen >= 1 always
        const float* xr = emb + (size_t)stok[xrow][posx] * EMB + xpart * 4;
        *(float4*)xdst = *(const float4*)xr;
    }
    __syncthreads();

    for (int t = 0; t < tlimit; t++) {
        const int nbt = nbt_s[t];
        const int jmax = min(max(nbt - grp * 8, 0), 8);
        const int act = g_act && (t < mylen);
        const int pred_lo = (grp * 8 + rA < nbt);
        const int pred_hi = (grp * 8 + rA + 4 < nbt);

        // ---- issue x(t+1) prefetch (consumed at staging below) ----
        float4 xa;
        {
            int tp = (t + 1 < tlimit) ? t + 1 : t;
            int posn = dir ? ((tp < xlen) ? xlen - 1 - tp : tp) : tp;
            const float* xrn = emb + (size_t)stok[xrow][posn] * EMB + xpart * 4;
            xa = *(const float4*)xrn;
        }

        // ---- zx hoist: Wih.x(t) partials, all waves, off critical path ----
        float4 zxp[8];
        #pragma unroll
        for (int j = 0; j < 8; j++) {
            float4 xv = *(const float4*)&xs[j * XSROW + lane * 4];
            float4 p;
            p.x = iD[0].x * xv.x; p.x = fmaf(iD[0].y, xv.y, p.x);
            p.x = fmaf(iD[0].z, xv.z, p.x); p.x = fmaf(iD[0].w, xv.w, p.x);
            p.y = iD[1].x * xv.x; p.y = fmaf(iD[1].y, xv.y, p.y);
            p.y = fmaf(iD[1].z, xv.z, p.y); p.y = fmaf(iD[1].w, xv.w, p.y);
            p.z = iD[2].x * xv.x; p.z = fmaf(iD[2].y, xv.y, p.z);
            p.z = fmaf(iD[2].z, xv.z, p.z); p.z = fmaf(iD[2].w, xv.w, p.z);
            p.w = iD[3].x * xv.x; p.w = fmaf(iD[3].y, xv.y, p.w);
            p.w = fmaf(iD[3].z, xv.z, p.w); p.w = fmaf(iD[3].w, xv.w, p.w);
            zxp[j] = p;
        }

        // ---- flag wait: wave0 only; lane l watches slice l's flag line ----
        if (t > 0 && wave == 0) {
            const unsigned tgt = (unsigned)t;
            const unsigned* cp = pollbase + lane * 16;
            bool mydone = false;
            while (true) {
                if (!mydone)
                    mydone = __hip_atomic_load(cp, __ATOMIC_RELAXED,
                                               __HIP_MEMORY_SCOPE_AGENT) >= tgt;
                if (__ballot(mydone) == ~0ull) break;
                __builtin_amdgcn_s_sleep(1);
            }
        }
        __syncthreads();   // SYNC1: zx reads of xs done; cohort h(t) published

        // ---- stage h(t): 2 sc1 dwordx4 loads, one vmcnt; write x(t+1) ----
        {
            const char* baseD = (const char*)hping
                + ((size_t)(t & 1) * 2 * BB * HID + (size_t)dir * BB * HID) * 4;
            const char* fb = baseD + o_fb;
            const char* a0 = pred_lo ? baseD + o_lo : fb;
            const char* a1 = pred_hi ? baseD + o_hi : fb;
            float4 u0, u1;
            asm volatile(
                "global_load_dwordx4 %0, %2, off sc0 sc1\n\t"
                "global_load_dwordx4 %1, %3, off sc0 sc1\n\t"
                "s_waitcnt vmcnt(0)"
                : "=&v"(u0), "=&v"(u1)
                : "v"(a0), "v"(a1)
                : "memory");
            *(float4*)&hs[(rA    ) * HSROW + wbBase] = u0;
            *(float4*)&hs[(rA + 4) * HSROW + wbBase] = u1;
            *(float4*)xdst = xa;
        }
        __syncthreads();   // SYNC2: staging visible

        // ---- dot: Whh.h only; FULLY UNROLLED (constant j) so zxp stays
        //      in registers (r20 bug: runtime j -> scratch, rule #20) ----
        #pragma unroll
        for (int j = 0; j < 8; j++) {
            if (j < jmax) {   // wave-uniform guard (nbt,grp uniform)
                const float* hb = &hs[j * HSROW + rdoff];
                float4 h0 = *(const float4*)(hb);
                float4 h1 = *(const float4*)(hb + 4);
                float a0 = zxp[j].x, a1 = zxp[j].y, a2 = zxp[j].z, a3 = zxp[j].w;
                a0 = fmaf(wD[0][0].x, h0.x, a0); a0 = fmaf(wD[0][0].y, h0.y, a0);
                a0 = fmaf(wD[0][0].z, h0.z, a0); a0 = fmaf(wD[0][0].w, h0.w, a0);
                a0 = fmaf(wD[0][1].x, h1.x, a0); a0 = fmaf(wD[0][1].y, h1.y, a0);
                a0 = fmaf(wD[0][1].z, h1.z, a0); a0 = fmaf(wD[0][1].w, h1.w, a0);
                a1 = fmaf(wD[1][0].x, h0.x, a1); a1 = fmaf(wD[1][0].y, h0.y, a1);
                a1 = fmaf(wD[1][0].z, h0.z, a1); a1 = fmaf(wD[1][0].w, h0.w, a1);
                a1 = fmaf(wD[1][1].x, h1.x, a1); a1 = fmaf(wD[1][1].y, h1.y, a1);
                a1 = fmaf(wD[1][1].z, h1.z, a1); a1 = fmaf(wD[1][1].w, h1.w, a1);
                a2 = fmaf(wD[2][0].x, h0.x, a2); a2 = fmaf(wD[2][0].y, h0.y, a2);
                a2 = fmaf(wD[2][0].z, h0.z, a2); a2 = fmaf(wD[2][0].w, h0.w, a2);
                a2 = fmaf(wD[2][1].x, h1.x, a2); a2 = fmaf(wD[2][1].y, h1.y, a2);
                a2 = fmaf(wD[2][1].z, h1.z, a2); a2 = fmaf(wD[2][1].w, h1.w, a2);
                a3 = fmaf(wD[3][0].x, h0.x, a3); a3 = fmaf(wD[3][0].y, h0.y, a3);
                a3 = fmaf(wD[3][0].z, h0.z, a3); a3 = fmaf(wD[3][0].w, h0.w, a3);
                a3 = fmaf(wD[3][1].x, h1.x, a3); a3 = fmaf(wD[3][1].y, h1.y, a3);
                a3 = fmaf(wD[3][1].z, h1.z, a3); a3 = fmaf(wD[3][1].w, h1.w, a3);
                bool lo32 = (lane & 32) == 0;
                float tA = __shfl_xor(lo32 ? a2 : a0, 32);
                float tB = __shfl_xor(lo32 ? a3 : a1, 32);
                float rAq = (lo32 ? a0 : a2) + tA;
                float rBq = (lo32 ? a1 : a3) + tB;
                bool lo16 = (lane & 16) == 0;
                float tC = __shfl_xor(lo16 ? rBq : rAq, 16);
                float r  = (lo16 ? rAq : rBq) + tC;
                r += __shfl_xor(r, 8);
                r += __shfl_xor(r, 4);
                r += __shfl_xor(r, 2);
                r += __shfl_xor(r, 1);
                if ((lane & 15) == 0)
                    zw[wave * 132 + (lane >> 4) * 33 + j] = r;
            }
        }

        // ---- gates (read own wave's zw, no barrier needed); h-store ----
        float hn = 0.f;
        if (act) {
            float iv = zw[wave * 132 +  0 + gj] + bc[0];
            float fv = zw[wave * 132 + 33 + gj] + bc[1];
            float gv = zw[wave * 132 + 66 + gj] + bc[2];
            float ov = zw[wave * 132 + 99 + gj] + bc[3];
            float cn = sigmoidf_(fv) * cS + sigmoidf_(iv) * tanhf(gv);
            hn = sigmoidf_(ov) * tanhf(cn);
            cS = cn;
            __hip_atomic_store(hp + (size_t)(((t + 1) & 1) * 2) * BB * HID, hn,
                               __ATOMIC_RELAXED, __HIP_MEMORY_SCOPE_AGENT);
        }

        // ---- per-wave drain + LDS arrival; 8th arriver publishes flag ----
        asm volatile("s_waitcnt vmcnt(0)" ::: "memory");
        if (lane == 0) {
            unsigned old = atomicAdd(&lds_cnt, 1u);
            if (old == (unsigned)(t * 8 + 7) && t < tlimit - 1)
                __hip_atomic_store(myflag, (unsigned)(t + 1),
                                   __ATOMIC_RELAXED, __HIP_MEMORY_SCOPE_AGENT);
        }

        // ---- history store AFTER arrive (latency hides in next phase) ----
        if (act) hout[(size_t)t * HID] = hn;
    }
}

// ---------------------------------------------------------------------------
// K3: feats — one wave per (b,t), all 64 lanes, LDS transpose-reduce.
// ---------------------------------------------------------------------------
__global__ __launch_bounds__(256) void k_feats(
    const int* __restrict__ lengths,
    const float* __restrict__ hbuf,  // [2][B][T][512]
    const float* __restrict__ Wout,  // [20][1024]
    const float* __restrict__ bout,  // [20]
    float* __restrict__ feats)       // [B][T][20]
{
    const int w = threadIdx.x >> 6;
    const int lane = threadIdx.x & 63;
    const int idx = blockIdx.x * 4 + w;
    const int b = idx >> 8, t = idx & 255;
    const int len = lengths[b];

    __shared__ float red[4][64][21];

    float acc[KTAGS];
    bool active = (t < len);
    if (active) {
        const int ofs = lane * 16;
        const float* src = (ofs < HID)
            ? hbuf + ((size_t)b * TT + t) * HID + ofs
            : hbuf + ((size_t)(BB + b) * TT + (len - 1 - t)) * HID + (ofs - HID);
        float x[16];
        #pragma unroll
        for (int q = 0; q < 4; q++) {
            float4 v = *(const float4*)(src + 4 * q);
            x[4 * q] = v.x; x[4 * q + 1] = v.y; x[4 * q + 2] = v.z; x[4 * q + 3] = v.w;
        }
        #pragma unroll
        for (int k = 0; k < KTAGS; k++) {
            const float* wr = Wout + (size_t)k * (2 * HID) + ofs;
            float a = 0.f;
            #pragma unroll
            for (int q = 0; q < 4; q++) {
                float4 v = *(const float4*)(wr + 4 * q);
                a = fmaf(x[4 * q], v.x, a);
                a = fmaf(x[4 * q + 1], v.y, a);
                a = fmaf(x[4 * q + 2], v.z, a);
                a = fmaf(x[4 * q + 3], v.w, a);
            }
            acc[k] = a;
        }
    } else {
        #pragma unroll
        for (int k = 0; k < KTAGS; k++) acc[k] = 0.f;
    }
    #pragma unroll
    for (int k = 0; k < KTAGS; k++) red[w][lane][k] = acc[k];
    __syncthreads();

    if (active && lane < KTAGS) {
        float s = bout[lane];
        #pragma unroll 8
        for (int l = 0; l < 64; l++) s += red[w][l][lane];
        feats[(size_t)idx * KTAGS + lane] = s;
    }
}

// ---------------------------------------------------------------------------
// K4: Viterbi — LDS backpointers, double-buffered fv, feats prefetch.
// ---------------------------------------------------------------------------
__global__ __launch_bounds__(64) void k_viterbi(
    const int* __restrict__ lengths,
    const float* __restrict__ trans,  // [20][20]
    const float* __restrict__ feats,  // [B][T][20]
    float* __restrict__ out)          // [32 scores][32*257 path]
{
    const int b = blockIdx.x;
    const int len = lengths[b];
    const int tid = threadIdx.x;

    __shared__ float tr[KTAGS * KTAGS];
    __shared__ float fvb[2][KTAGS];
    __shared__ int   bp[TT][KTAGS];
    __shared__ float term[KTAGS];

    for (int i = tid; i < KTAGS * KTAGS; i += 64) tr[i] = trans[i];
    if (tid < KTAGS) fvb[0][tid] = (tid == START_TAG) ? 0.f : NEGV;
    __syncthreads();

    float ft = (tid < KTAGS) ? feats[((size_t)b * TT) * KTAGS + tid] : 0.f;
    for (int t = 0; t < len; t++) {
        float ftn = (tid < KTAGS && t + 1 < len)
                  ? feats[((size_t)b * TT + t + 1) * KTAGS + tid] : 0.f;
        if (tid < KTAGS) {
            const float* fvc = fvb[t & 1];
            float best = -1e30f; int bi = 0;
            #pragma unroll
            for (int p = 0; p < KTAGS; p++) {
                float s = fvc[p] + tr[tid * KTAGS + p];
                if (s > best) { best = s; bi = p; }
            }
            fvb[(t + 1) & 1][tid] = best + ft;
            bp[t][tid] = bi;
        }
        ft = ftn;
        __syncthreads();
    }

    if (tid < KTAGS) term[tid] = fvb[len & 1][tid] + tr[END_TAG * KTAGS + tid];
    __syncthreads();

    if (tid == 0) {
        int bt_ = 0; float best = term[0];
        for (int k = 1; k < KTAGS; k++)
            if (term[k] > best) { best = term[k]; bt_ = k; }
        out[b] = best;
        float* path = out + BB + (size_t)b * (TT + 1);
        path[TT] = (float)bt_;
        int cur = bt_;
        for (int t = TT - 1; t >= 0; t--) {
            int src = t - (TT - len);
            if (src >= 0) cur = bp[src][cur];
            else          cur = KTAGS;
            path[t] = (float)cur;
        }
    }
}

// ---------------------------------------------------------------------------
extern "C" void kernel_launch(void* const* d_in, const int* in_sizes, int n_in,
                              void* d_out, int out_size, void* d_ws, size_t ws_size,
                              hipStream_t stream) {
    const int*   sentence = (const int*)d_in[0];
    const int*   lengths  = (const int*)d_in[1];
    const float* emb      = (const float*)d_in[2];
    const float* Wf_ih    = (const float*)d_in[3];
    const float* Wf_hh    = (const float*)d_in[4];
    const float* bf_ih    = (const float*)d_in[5];
    const float* bf_hh    = (const float*)d_in[6];
    const float* Wb_ih    = (const float*)d_in[7];
    const float* Wb_hh    = (const float*)d_in[8];
    const float* bb_ih    = (const float*)d_in[9];
    const float* bb_hh    = (const float*)d_in[10];
    const float* Wout     = (const float*)d_in[11];
    const float* bout     = (const float*)d_in[12];
    const float* trans    = (const float*)d_in[13];
    float* out = (float*)d_out;

    // workspace layout
    float*    hping = (float*)d_ws;                              // 65536 floats (256KB)
    unsigned* flags = (unsigned*)((char*)d_ws + 262144);         // 32KB (512 x 64B lines)
    float*    hbuf  = (float*)((char*)d_ws + 262144 + 32768);    // 2*32*256*512 floats
    float*    feats = hbuf + (size_t)2 * BB * TT * HID;          // 32*256*20

    (void)hipMemsetAsync(d_ws, 0, 262144 + 32768, stream);

    hipLaunchKernelGGL(k_lstm_persist, dim3(512), dim3(512), 0, stream,
                       lengths, sentence, emb, Wf_hh, Wb_hh, Wf_ih, Wb_ih,
                       bf_ih, bf_hh, bb_ih, bb_hh, hping, flags, hbuf);
    hipLaunchKernelGGL(k_feats, dim3(BB * TT / 4), dim3(256), 0, stream,
                       lengths, hbuf, Wout, bout, feats);
    hipLaunchKernelGGL(k_viterbi, dim3(BB), dim3(64), 0, stream,
                       lengths, trans, feats, out);
}

// Round 15
// 1797.380 us; speedup vs baseline: 1.9459x; 1.2085x over previous
//
#include <hip/hip_runtime.h>
#include <math.h>

#define VOCAB 50000
#define EMB 256
#define HID 512
#define KTAGS 20
#define START_TAG 18
#define END_TAG 19
#define BB 32
#define TT 256
#define NEGV -10000.0f
#define HSROW 644   // 512 phys + skew (4 per 16-float block)
#define XSROW 264   // 256 + 8 skew

__device__ __forceinline__ float sigmoidf_(float x) { return 1.0f / (1.0f + expf(-x)); }

// ---------------------------------------------------------------------------
// K2 r18 (REVERT-AND-SECURE): DIRECTION-SPLIT persistent LSTM.
//   512 WGs x 512 thr (2/CU). WG = (dir, slice, grp). Cohort = (dir,grp):
//   64 slice-WGs exchanging h through a 2-parity hping slot, step-barriered.
//   Measured 1665us (round 7) — best of all protocol/schedule variants:
//     r17 sentinel dataflow  2508us (wide poll storms LLC)
//     r19 per-thread poll    3379us (divergent polls run at WAVE granularity)
//     r20 zx-hoist           3130us (runtime-indexed zxp -> scratch, rule #20)
//     r21 zx-hoist fixed     2011us (32-reg live range chokes regalloc)
//   Lesson: narrow poll (one wave), minimal live state, 3 barriers, fused
//   DOTRED. The residual ~4us/step is publish+observe+load LLC latency and
//   max-of-64 WG skew — protocol variants do not beat it.
// ---------------------------------------------------------------------------
__global__ __launch_bounds__(512, 4) void k_lstm_persist(
    const int* __restrict__ lengths,
    const int* __restrict__ sentence,  // [32][256]
    const float* __restrict__ emb,     // [VOCAB][256]
    const float* __restrict__ Wf_hh, const float* __restrict__ Wb_hh,
    const float* __restrict__ Wf_ih, const float* __restrict__ Wb_ih,
    const float* __restrict__ bf_ih, const float* __restrict__ bf_hh,
    const float* __restrict__ bb_ih, const float* __restrict__ bb_hh,
    float* __restrict__ hping,         // [2 parity][2 dir][32][512]
    unsigned* __restrict__ flags,      // [2 dir][4 grp][64 slice][16 uints]
    float* __restrict__ hbuf)          // [2][32][256][512]
{
    const int wg = blockIdx.x;             // 0..511
    const int dir = wg >> 8;               // 0=F, 1=B
    const int slice = (wg & 255) >> 2;     // unit slice 0..63
    const int grp = wg & 3;                // sorted batch group 0..3
    const int tid = threadIdx.x;
    const int wave = tid >> 6;             // 0..7 = local unit
    const int lane = tid & 63;             // k-slice
    const int u_glob = slice * 8 + wave;   // 0..511

    const float* Whh  = dir ? Wb_hh : Wf_hh;
    const float* WihP = dir ? Wb_ih : Wf_ih;
    const float* bihP = dir ? bb_ih : bf_ih;
    const float* bhhP = dir ? bb_hh : bf_hh;

    // recurrent weights: 8 h-floats per lane per gate (one dir only)
    float4 wD[4][2];
    #pragma unroll
    for (int c = 0; c < 4; c++) {
        const float4* wr = (const float4*)(Whh + (size_t)(c * HID + u_glob) * HID + lane * 8);
        wD[c][0] = wr[0]; wD[c][1] = wr[1];
    }
    // input weights: 4 x-floats per lane per gate
    float4 iD[4];
    #pragma unroll
    for (int c = 0; c < 4; c++)
        iD[c] = *(const float4*)(WihP + (size_t)(c * HID + u_glob) * EMB + lane * 4);
    // biases for this wave's unit
    float bc[4];
    #pragma unroll
    for (int c = 0; c < 4; c++)
        bc[c] = bihP[c * HID + u_glob] + bhhP[c * HID + u_glob];

    __shared__ float hs[8 * HSROW];        // 8 batch rows of h (this dir)
    __shared__ float xs[8 * XSROW];        // 8 batch rows of x (this dir)
    __shared__ float zw[8 * 132];          // [wave][gate*33 + j]
    __shared__ int stok[8][TT];            // tokens for group's 8 sorted batches
    __shared__ int lens_raw[32];
    __shared__ int order_s[32];
    __shared__ int lens_s[32];
    __shared__ int nbt_s[TT];

    if (tid < 32) lens_raw[tid] = lengths[tid];
    __syncthreads();
    if (tid < 32) {
        int me = lens_raw[tid], rank = 0;
        #pragma unroll 4
        for (int o = 0; o < 32; o++) {
            int lo = lens_raw[o];
            rank += (lo > me || (lo == me && o < tid)) ? 1 : 0;
        }
        order_s[rank] = tid;
        lens_s[rank] = me;
    }
    if (tid >= 256) {
        int t = tid - 256, c = 0;
        #pragma unroll 4
        for (int b = 0; b < 32; b++) c += (lens_raw[b] > t) ? 1 : 0;
        nbt_s[t] = c;
    }
    __syncthreads();
    for (int i = tid; i < 8 * TT; i += 512) {
        int j = i >> 8, c = i & 255;
        stok[j][c] = sentence[order_s[grp * 8 + j] * TT + c];
    }
    __syncthreads();

    const int tlimit = lens_s[grp * 8];

    // gate identity: lanes 0..7 = local sorted pos within group
    const int gj = lane & 7;
    const int g_act = (lane < 8);
    const int p_sort = grp * 8 + gj;
    const int mylen = lens_s[p_sort];
    const int mybat = order_s[p_sort];
    float* hout = hbuf + (size_t)(dir * BB + mybat) * TT * HID + u_glob;
    float* hp   = hping + (size_t)dir * BB * HID + (size_t)mybat * HID + u_glob; // parity-0 base

    // h staging: 2 slots/thread. kq = tid&127, rA = tid>>7 (0..3)
    const int kq = tid & 127;
    const int rA = tid >> 7;
    const int wbBase = 4 * kq + 4 * (kq >> 2);
    const int sb_lo = order_s[grp * 8 + rA];
    const int sb_hi = order_s[grp * 8 + rA + 4];
    const int sb0   = order_s[grp * 8];   // longest batch in group: always live
    const size_t o_lo = (size_t)sb_lo * 2048 + (size_t)kq * 16;
    const size_t o_hi = (size_t)sb_hi * 2048 + (size_t)kq * 16;
    const size_t o_fb = (size_t)sb0   * 2048 + (size_t)kq * 16;

    // x staging: row = wave (tid>>6), xpart = tid&63 (4 floats each)
    const int xrow = tid >> 6;
    const int xpart = tid & 63;
    const int xlen = lens_s[grp * 8 + xrow];
    float* xdst = &xs[xrow * XSROW + xpart * 4];

    const int rdoff = 8 * lane + 4 * (lane >> 1);

    float cS = 0.f;
    unsigned* myflag = flags + ((size_t)(dir * 4 + grp) * 64 + slice) * 16;
    const unsigned* pollbase = flags + (size_t)(dir * 4 + grp) * 64 * 16;

#define DOTRED()                                                               \
    for (int j = 0; j < jmax; j++) {                                           \
        const float* hb = &hs[j * HSROW + rdoff];                              \
        float4 h0 = *(const float4*)(hb);                                      \
        float4 h1 = *(const float4*)(hb + 4);                                  \
        float4 xv = *(const float4*)&xs[j * XSROW + lane * 4];                 \
        float a0 = 0.f, a1 = 0.f, a2 = 0.f, a3 = 0.f;                          \
        a0 = fmaf(wD[0][0].x, h0.x, a0); a0 = fmaf(wD[0][0].y, h0.y, a0);      \
        a0 = fmaf(wD[0][0].z, h0.z, a0); a0 = fmaf(wD[0][0].w, h0.w, a0);      \
        a0 = fmaf(wD[0][1].x, h1.x, a0); a0 = fmaf(wD[0][1].y, h1.y, a0);      \
        a0 = fmaf(wD[0][1].z, h1.z, a0); a0 = fmaf(wD[0][1].w, h1.w, a0);      \
        a0 = fmaf(iD[0].x, xv.x, a0);    a0 = fmaf(iD[0].y, xv.y, a0);         \
        a0 = fmaf(iD[0].z, xv.z, a0);    a0 = fmaf(iD[0].w, xv.w, a0);         \
        a1 = fmaf(wD[1][0].x, h0.x, a1); a1 = fmaf(wD[1][0].y, h0.y, a1);      \
        a1 = fmaf(wD[1][0].z, h0.z, a1); a1 = fmaf(wD[1][0].w, h0.w, a1);      \
        a1 = fmaf(wD[1][1].x, h1.x, a1); a1 = fmaf(wD[1][1].y, h1.y, a1);      \
        a1 = fmaf(wD[1][1].z, h1.z, a1); a1 = fmaf(wD[1][1].w, h1.w, a1);      \
        a1 = fmaf(iD[1].x, xv.x, a1);    a1 = fmaf(iD[1].y, xv.y, a1);         \
        a1 = fmaf(iD[1].z, xv.z, a1);    a1 = fmaf(iD[1].w, xv.w, a1);         \
        a2 = fmaf(wD[2][0].x, h0.x, a2); a2 = fmaf(wD[2][0].y, h0.y, a2);      \
        a2 = fmaf(wD[2][0].z, h0.z, a2); a2 = fmaf(wD[2][0].w, h0.w, a2);      \
        a2 = fmaf(wD[2][1].x, h1.x, a2); a2 = fmaf(wD[2][1].y, h1.y, a2);      \
        a2 = fmaf(wD[2][1].z, h1.z, a2); a2 = fmaf(wD[2][1].w, h1.w, a2);      \
        a2 = fmaf(iD[2].x, xv.x, a2);    a2 = fmaf(iD[2].y, xv.y, a2);         \
        a2 = fmaf(iD[2].z, xv.z, a2);    a2 = fmaf(iD[2].w, xv.w, a2);         \
        a3 = fmaf(wD[3][0].x, h0.x, a3); a3 = fmaf(wD[3][0].y, h0.y, a3);      \
        a3 = fmaf(wD[3][0].z, h0.z, a3); a3 = fmaf(wD[3][0].w, h0.w, a3);      \
        a3 = fmaf(wD[3][1].x, h1.x, a3); a3 = fmaf(wD[3][1].y, h1.y, a3);      \
        a3 = fmaf(wD[3][1].z, h1.z, a3); a3 = fmaf(wD[3][1].w, h1.w, a3);      \
        a3 = fmaf(iD[3].x, xv.x, a3);    a3 = fmaf(iD[3].y, xv.y, a3);         \
        a3 = fmaf(iD[3].z, xv.z, a3);    a3 = fmaf(iD[3].w, xv.w, a3);         \
        bool lo32 = (lane & 32) == 0;                                          \
        float tA = __shfl_xor(lo32 ? a2 : a0, 32);                             \
        float tB = __shfl_xor(lo32 ? a3 : a1, 32);                             \
        float rAq = (lo32 ? a0 : a2) + tA;                                     \
        float rBq = (lo32 ? a1 : a3) + tB;                                     \
        bool lo16 = (lane & 16) == 0;                                          \
        float tC = __shfl_xor(lo16 ? rBq : rAq, 16);                           \
        float r  = (lo16 ? rAq : rBq) + tC;                                    \
        r += __shfl_xor(r, 8);                                                 \
        r += __shfl_xor(r, 4);                                                 \
        r += __shfl_xor(r, 2);                                                 \
        r += __shfl_xor(r, 1);                                                 \
        if ((lane & 15) == 0)                                                  \
            zw[wave * 132 + (lane >> 4) * 33 + j] = r;                         \
    }

    for (int t = 0; t < tlimit; t++) {
        const int nbt = nbt_s[t];
        const int jmax = min(max(nbt - grp * 8, 0), 8);
        const int act = g_act && (t < mylen);
        const int pred_lo = (grp * 8 + rA < nbt);
        const int pred_hi = (grp * 8 + rA + 4 < nbt);

        // ---- prefetch x row (barrier-independent; consumed after staging) --
        int posx = dir ? ((t < xlen) ? xlen - 1 - t : t) : t;
        const float* xr = emb + (size_t)stok[xrow][posx] * EMB + xpart * 4;
        float4 xa = *(const float4*)xr;

        // ---- flag wait: wave0 only; lane l watches slice l's flag line ----
        if (t > 0 && wave == 0) {
            const unsigned tgt = (unsigned)t;
            const unsigned* cp = pollbase + lane * 16;
            bool mydone = false;
            while (true) {
                if (!mydone)
                    mydone = __hip_atomic_load(cp, __ATOMIC_RELAXED,
                                               __HIP_MEMORY_SCOPE_AGENT) >= tgt;
                if (__ballot(mydone) == ~0ull) break;
                __builtin_amdgcn_s_sleep(1);
            }
        }
        __syncthreads();

        // ---- stage h(t): 2 sc1 dwordx4 loads, one vmcnt; plus x ----
        {
            const char* baseD = (const char*)hping
                + ((size_t)(t & 1) * 2 * BB * HID + (size_t)dir * BB * HID) * 4;
            const char* fb = baseD + o_fb;
            const char* a0 = pred_lo ? baseD + o_lo : fb;
            const char* a1 = pred_hi ? baseD + o_hi : fb;
            float4 u0, u1;
            asm volatile(
                "global_load_dwordx4 %0, %2, off sc0 sc1\n\t"
                "global_load_dwordx4 %1, %3, off sc0 sc1\n\t"
                "s_waitcnt vmcnt(0)"
                : "=&v"(u0), "=&v"(u1)
                : "v"(a0), "v"(a1)
                : "memory");
            *(float4*)&hs[(rA    ) * HSROW + wbBase] = u0;
            *(float4*)&hs[(rA + 4) * HSROW + wbBase] = u1;
            *(float4*)xdst = xa;
        }
        __syncthreads();

        // ---- dot: Whh.h + Wih.x fused (one dir) ----
        DOTRED();

        // ---- gates; exchange (hping) store only ----
        float hn = 0.f;
        if (act) {
            float iv = zw[wave * 132 +  0 + gj] + bc[0];
            float fv = zw[wave * 132 + 33 + gj] + bc[1];
            float gv = zw[wave * 132 + 66 + gj] + bc[2];
            float ov = zw[wave * 132 + 99 + gj] + bc[3];
            float cn = sigmoidf_(fv) * cS + sigmoidf_(iv) * tanhf(gv);
            hn = sigmoidf_(ov) * tanhf(cn);
            cS = cn;
            __hip_atomic_store(hp + (size_t)(((t + 1) & 1) * 2) * BB * HID, hn,
                               __ATOMIC_RELAXED, __HIP_MEMORY_SCOPE_AGENT);
        }

        // ---- drain exchange stores, then single flag store (no RMW) ----
        __syncthreads();
        if (t < tlimit - 1 && tid == 0)
            __hip_atomic_store(myflag, (unsigned)(t + 1),
                               __ATOMIC_RELAXED, __HIP_MEMORY_SCOPE_AGENT);

        // ---- history store AFTER flag (latency hides in next wait) ----
        if (act) hout[(size_t)t * HID] = hn;
    }
#undef DOTRED
}

// ---------------------------------------------------------------------------
// K3: feats — one wave per (b,t), all 64 lanes, LDS transpose-reduce.
// ---------------------------------------------------------------------------
__global__ __launch_bounds__(256) void k_feats(
    const int* __restrict__ lengths,
    const float* __restrict__ hbuf,  // [2][B][T][512]
    const float* __restrict__ Wout,  // [20][1024]
    const float* __restrict__ bout,  // [20]
    float* __restrict__ feats)       // [B][T][20]
{
    const int w = threadIdx.x >> 6;
    const int lane = threadIdx.x & 63;
    const int idx = blockIdx.x * 4 + w;
    const int b = idx >> 8, t = idx & 255;
    const int len = lengths[b];

    __shared__ float red[4][64][21];

    float acc[KTAGS];
    bool active = (t < len);
    if (active) {
        const int ofs = lane * 16;
        const float* src = (ofs < HID)
            ? hbuf + ((size_t)b * TT + t) * HID + ofs
            : hbuf + ((size_t)(BB + b) * TT + (len - 1 - t)) * HID + (ofs - HID);
        float x[16];
        #pragma unroll
        for (int q = 0; q < 4; q++) {
            float4 v = *(const float4*)(src + 4 * q);
            x[4 * q] = v.x; x[4 * q + 1] = v.y; x[4 * q + 2] = v.z; x[4 * q + 3] = v.w;
        }
        #pragma unroll
        for (int k = 0; k < KTAGS; k++) {
            const float* wr = Wout + (size_t)k * (2 * HID) + ofs;
            float a = 0.f;
            #pragma unroll
            for (int q = 0; q < 4; q++) {
                float4 v = *(const float4*)(wr + 4 * q);
                a = fmaf(x[4 * q], v.x, a);
                a = fmaf(x[4 * q + 1], v.y, a);
                a = fmaf(x[4 * q + 2], v.z, a);
                a = fmaf(x[4 * q + 3], v.w, a);
            }
            acc[k] = a;
        }
    } else {
        #pragma unroll
        for (int k = 0; k < KTAGS; k++) acc[k] = 0.f;
    }
    #pragma unroll
    for (int k = 0; k < KTAGS; k++) red[w][lane][k] = acc[k];
    __syncthreads();

    if (active && lane < KTAGS) {
        float s = bout[lane];
        #pragma unroll 8
        for (int l = 0; l < 64; l++) s += red[w][l][lane];
        feats[(size_t)idx * KTAGS + lane] = s;
    }
}

// ---------------------------------------------------------------------------
// K4: Viterbi — LDS backpointers, double-buffered fv, feats prefetch.
// ---------------------------------------------------------------------------
__global__ __launch_bounds__(64) void k_viterbi(
    const int* __restrict__ lengths,
    const float* __restrict__ trans,  // [20][20]
    const float* __restrict__ feats,  // [B][T][20]
    float* __restrict__ out)          // [32 scores][32*257 path]
{
    const int b = blockIdx.x;
    const int len = lengths[b];
    const int tid = threadIdx.x;

    __shared__ float tr[KTAGS * KTAGS];
    __shared__ float fvb[2][KTAGS];
    __shared__ int   bp[TT][KTAGS];
    __shared__ float term[KTAGS];

    for (int i = tid; i < KTAGS * KTAGS; i += 64) tr[i] = trans[i];
    if (tid < KTAGS) fvb[0][tid] = (tid == START_TAG) ? 0.f : NEGV;
    __syncthreads();

    float ft = (tid < KTAGS) ? feats[((size_t)b * TT) * KTAGS + tid] : 0.f;
    for (int t = 0; t < len; t++) {
        float ftn = (tid < KTAGS && t + 1 < len)
                  ? feats[((size_t)b * TT + t + 1) * KTAGS + tid] : 0.f;
        if (tid < KTAGS) {
            const float* fvc = fvb[t & 1];
            float best = -1e30f; int bi = 0;
            #pragma unroll
            for (int p = 0; p < KTAGS; p++) {
                float s = fvc[p] + tr[tid * KTAGS + p];
                if (s > best) { best = s; bi = p; }
            }
            fvb[(t + 1) & 1][tid] = best + ft;
            bp[t][tid] = bi;
        }
        ft = ftn;
        __syncthreads();
    }

    if (tid < KTAGS) term[tid] = fvb[len & 1][tid] + tr[END_TAG * KTAGS + tid];
    __syncthreads();

    if (tid == 0) {
        int bt_ = 0; float best = term[0];
        for (int k = 1; k < KTAGS; k++)
            if (term[k] > best) { best = term[k]; bt_ = k; }
        out[b] = best;
        float* path = out + BB + (size_t)b * (TT + 1);
        path[TT] = (float)bt_;
        int cur = bt_;
        for (int t = TT - 1; t >= 0; t--) {
            int src = t - (TT - len);
            if (src >= 0) cur = bp[src][cur];
            else          cur = KTAGS;
            path[t] = (float)cur;
        }
    }
}

// ---------------------------------------------------------------------------
extern "C" void kernel_launch(void* const* d_in, const int* in_sizes, int n_in,
                              void* d_out, int out_size, void* d_ws, size_t ws_size,
                              hipStream_t stream) {
    const int*   sentence = (const int*)d_in[0];
    const int*   lengths  = (const int*)d_in[1];
    const float* emb      = (const float*)d_in[2];
    const float* Wf_ih    = (const float*)d_in[3];
    const float* Wf_hh    = (const float*)d_in[4];
    const float* bf_ih    = (const float*)d_in[5];
    const float* bf_hh    = (const float*)d_in[6];
    const float* Wb_ih    = (const float*)d_in[7];
    const float* Wb_hh    = (const float*)d_in[8];
    const float* bb_ih    = (const float*)d_in[9];
    const float* bb_hh    = (const float*)d_in[10];
    const float* Wout     = (const float*)d_in[11];
    const float* bout     = (const float*)d_in[12];
    const float* trans    = (const float*)d_in[13];
    float* out = (float*)d_out;

    // workspace layout
    float*    hping = (float*)d_ws;                              // 65536 floats (256KB)
    unsigned* flags = (unsigned*)((char*)d_ws + 262144);         // 32KB (512 x 64B lines)
    float*    hbuf  = (float*)((char*)d_ws + 262144 + 32768);    // 2*32*256*512 floats
    float*    feats = hbuf + (size_t)2 * BB * TT * HID;          // 32*256*20

    (void)hipMemsetAsync(d_ws, 0, 262144 + 32768, stream);

    hipLaunchKernelGGL(k_lstm_persist, dim3(512), dim3(512), 0, stream,
                       lengths, sentence, emb, Wf_hh, Wb_hh, Wf_ih, Wb_ih,
                       bf_ih, bf_hh, bb_ih, bb_hh, hping, flags, hbuf);
    hipLaunchKernelGGL(k_feats, dim3(BB * TT / 4), dim3(256), 0, stream,
                       lengths, hbuf, Wout, bout, feats);
    hipLaunchKernelGGL(k_viterbi, dim3(BB), dim3(64), 0, stream,
                       lengths, trans, feats, out);
}

// Round 16
// 1775.813 us; speedup vs baseline: 1.9695x; 1.0121x over previous
//
#include <hip/hip_runtime.h>
#include <math.h>

#define VOCAB 50000
#define EMB 256
#define HID 512
#define KTAGS 20
#define START_TAG 18
#define END_TAG 19
#define BB 32
#define TT 256
#define NEGV -10000.0f
#define HSROW 644   // 512 phys + skew (4 per 16-float block)
#define XSROW 264   // 256 + 8 skew

__device__ __forceinline__ float sigmoidf_(float x) { return 1.0f / (1.0f + expf(-x)); }

// ---------------------------------------------------------------------------
// K2 r22: r18 protocol EXACTLY (wave0-poll + flag lines, 3 barriers, fused
//   DOTRED, minimal live state — measured 1657us) with ONE change:
//   SINGLE-STORE EXCHANGE. hbuf[t] replaces hping as the exchange medium.
//     - producer: ONE agent-scope store h(t) -> hbuf[bat][t][u] BEFORE the
//       drain barrier (was: hping store before drain + plain hbuf store
//       after flag). One store stream instead of two.
//     - consumer at step t: loads h(t) = hbuf[..][t-1][..] (per-t slot ->
//       no parity WAR hazard at all); t==0 zero-fills (h(0)=0).
//     - flag semantics unchanged: flag>=t => all producers drained step
//       t-1 stores to LLC => hbuf[t-1] readable. Drain covers the same
//       8-scattered-line store pattern as before.
//   Predicted: WRITE 140->~76MB, dur 1657->~1600us. If neutral: the
//   latency plateau of this decomposition is confirmed (register file
//   forces 64-way unit split; 256 serial all-to-all steps at LLC latency).
// ---------------------------------------------------------------------------
__global__ __launch_bounds__(512, 4) void k_lstm_persist(
    const int* __restrict__ lengths,
    const int* __restrict__ sentence,  // [32][256]
    const float* __restrict__ emb,     // [VOCAB][256]
    const float* __restrict__ Wf_hh, const float* __restrict__ Wb_hh,
    const float* __restrict__ Wf_ih, const float* __restrict__ Wb_ih,
    const float* __restrict__ bf_ih, const float* __restrict__ bf_hh,
    const float* __restrict__ bb_ih, const float* __restrict__ bb_hh,
    float* __restrict__ hping,         // retained in signature; unused (layout compat)
    unsigned* __restrict__ flags,      // [2 dir][4 grp][64 slice][16 uints]
    float* __restrict__ hbuf)          // [2][32][256][512] — exchange + history
{
    const int wg = blockIdx.x;             // 0..511
    const int dir = wg >> 8;               // 0=F, 1=B
    const int slice = (wg & 255) >> 2;     // unit slice 0..63
    const int grp = wg & 3;                // sorted batch group 0..3
    const int tid = threadIdx.x;
    const int wave = tid >> 6;             // 0..7 = local unit
    const int lane = tid & 63;             // k-slice
    const int u_glob = slice * 8 + wave;   // 0..511

    const float* Whh  = dir ? Wb_hh : Wf_hh;
    const float* WihP = dir ? Wb_ih : Wf_ih;
    const float* bihP = dir ? bb_ih : bf_ih;
    const float* bhhP = dir ? bb_hh : bf_hh;

    // recurrent weights: 8 h-floats per lane per gate (one dir only)
    float4 wD[4][2];
    #pragma unroll
    for (int c = 0; c < 4; c++) {
        const float4* wr = (const float4*)(Whh + (size_t)(c * HID + u_glob) * HID + lane * 8);
        wD[c][0] = wr[0]; wD[c][1] = wr[1];
    }
    // input weights: 4 x-floats per lane per gate
    float4 iD[4];
    #pragma unroll
    for (int c = 0; c < 4; c++)
        iD[c] = *(const float4*)(WihP + (size_t)(c * HID + u_glob) * EMB + lane * 4);
    // biases for this wave's unit
    float bc[4];
    #pragma unroll
    for (int c = 0; c < 4; c++)
        bc[c] = bihP[c * HID + u_glob] + bhhP[c * HID + u_glob];

    __shared__ float hs[8 * HSROW];        // 8 batch rows of h (this dir)
    __shared__ float xs[8 * XSROW];        // 8 batch rows of x (this dir)
    __shared__ float zw[8 * 132];          // [wave][gate*33 + j]
    __shared__ int stok[8][TT];            // tokens for group's 8 sorted batches
    __shared__ int lens_raw[32];
    __shared__ int order_s[32];
    __shared__ int lens_s[32];
    __shared__ int nbt_s[TT];

    if (tid < 32) lens_raw[tid] = lengths[tid];
    __syncthreads();
    if (tid < 32) {
        int me = lens_raw[tid], rank = 0;
        #pragma unroll 4
        for (int o = 0; o < 32; o++) {
            int lo = lens_raw[o];
            rank += (lo > me || (lo == me && o < tid)) ? 1 : 0;
        }
        order_s[rank] = tid;
        lens_s[rank] = me;
    }
    if (tid >= 256) {
        int t = tid - 256, c = 0;
        #pragma unroll 4
        for (int b = 0; b < 32; b++) c += (lens_raw[b] > t) ? 1 : 0;
        nbt_s[t] = c;
    }
    __syncthreads();
    for (int i = tid; i < 8 * TT; i += 512) {
        int j = i >> 8, c = i & 255;
        stok[j][c] = sentence[order_s[grp * 8 + j] * TT + c];
    }
    __syncthreads();

    const int tlimit = lens_s[grp * 8];

    // gate identity: lanes 0..7 = local sorted pos within group
    const int gj = lane & 7;
    const int g_act = (lane < 8);
    const int p_sort = grp * 8 + gj;
    const int mylen = lens_s[p_sort];
    const int mybat = order_s[p_sort];
    float* hout = hbuf + (size_t)(dir * BB + mybat) * TT * HID + u_glob;

    // h staging: 2 slots/thread. kq = tid&127, rA = tid>>7 (0..3)
    const int kq = tid & 127;
    const int rA = tid >> 7;
    const int wbBase = 4 * kq + 4 * (kq >> 2);
    const int sb_lo = order_s[grp * 8 + rA];
    const int sb_hi = order_s[grp * 8 + rA + 4];
    const int sb0   = order_s[grp * 8];   // longest batch in group: always live
    const size_t BSTR = (size_t)TT * HID * 4;   // bytes per batch row of hbuf
    const size_t o_lo = (size_t)sb_lo * BSTR + (size_t)kq * 16;
    const size_t o_hi = (size_t)sb_hi * BSTR + (size_t)kq * 16;
    const size_t o_fb = (size_t)sb0   * BSTR + (size_t)kq * 16;
    const char*  hbase = (const char*)hbuf + (size_t)dir * BB * BSTR;

    // x staging: row = wave (tid>>6), xpart = tid&63 (4 floats each)
    const int xrow = tid >> 6;
    const int xpart = tid & 63;
    const int xlen = lens_s[grp * 8 + xrow];
    float* xdst = &xs[xrow * XSROW + xpart * 4];

    const int rdoff = 8 * lane + 4 * (lane >> 1);

    float cS = 0.f;
    unsigned* myflag = flags + ((size_t)(dir * 4 + grp) * 64 + slice) * 16;
    const unsigned* pollbase = flags + (size_t)(dir * 4 + grp) * 64 * 16;

#define DOTRED()                                                               \
    for (int j = 0; j < jmax; j++) {                                           \
        const float* hb = &hs[j * HSROW + rdoff];                              \
        float4 h0 = *(const float4*)(hb);                                      \
        float4 h1 = *(const float4*)(hb + 4);                                  \
        float4 xv = *(const float4*)&xs[j * XSROW + lane * 4];                 \
        float a0 = 0.f, a1 = 0.f, a2 = 0.f, a3 = 0.f;                          \
        a0 = fmaf(wD[0][0].x, h0.x, a0); a0 = fmaf(wD[0][0].y, h0.y, a0);      \
        a0 = fmaf(wD[0][0].z, h0.z, a0); a0 = fmaf(wD[0][0].w, h0.w, a0);      \
        a0 = fmaf(wD[0][1].x, h1.x, a0); a0 = fmaf(wD[0][1].y, h1.y, a0);      \
        a0 = fmaf(wD[0][1].z, h1.z, a0); a0 = fmaf(wD[0][1].w, h1.w, a0);      \
        a0 = fmaf(iD[0].x, xv.x, a0);    a0 = fmaf(iD[0].y, xv.y, a0);         \
        a0 = fmaf(iD[0].z, xv.z, a0);    a0 = fmaf(iD[0].w, xv.w, a0);         \
        a1 = fmaf(wD[1][0].x, h0.x, a1); a1 = fmaf(wD[1][0].y, h0.y, a1);      \
        a1 = fmaf(wD[1][0].z, h0.z, a1); a1 = fmaf(wD[1][0].w, h0.w, a1);      \
        a1 = fmaf(wD[1][1].x, h1.x, a1); a1 = fmaf(wD[1][1].y, h1.y, a1);      \
        a1 = fmaf(wD[1][1].z, h1.z, a1); a1 = fmaf(wD[1][1].w, h1.w, a1);      \
        a1 = fmaf(iD[1].x, xv.x, a1);    a1 = fmaf(iD[1].y, xv.y, a1);         \
        a1 = fmaf(iD[1].z, xv.z, a1);    a1 = fmaf(iD[1].w, xv.w, a1);         \
        a2 = fmaf(wD[2][0].x, h0.x, a2); a2 = fmaf(wD[2][0].y, h0.y, a2);      \
        a2 = fmaf(wD[2][0].z, h0.z, a2); a2 = fmaf(wD[2][0].w, h0.w, a2);      \
        a2 = fmaf(wD[2][1].x, h1.x, a2); a2 = fmaf(wD[2][1].y, h1.y, a2);      \
        a2 = fmaf(wD[2][1].z, h1.z, a2); a2 = fmaf(wD[2][1].w, h1.w, a2);      \
        a2 = fmaf(iD[2].x, xv.x, a2);    a2 = fmaf(iD[2].y, xv.y, a2);         \
        a2 = fmaf(iD[2].z, xv.z, a2);    a2 = fmaf(iD[2].w, xv.w, a2);         \
        a3 = fmaf(wD[3][0].x, h0.x, a3); a3 = fmaf(wD[3][0].y, h0.y, a3);      \
        a3 = fmaf(wD[3][0].z, h0.z, a3); a3 = fmaf(wD[3][0].w, h0.w, a3);      \
        a3 = fmaf(wD[3][1].x, h1.x, a3); a3 = fmaf(wD[3][1].y, h1.y, a3);      \
        a3 = fmaf(wD[3][1].z, h1.z, a3); a3 = fmaf(wD[3][1].w, h1.w, a3);      \
        a3 = fmaf(iD[3].x, xv.x, a3);    a3 = fmaf(iD[3].y, xv.y, a3);         \
        a3 = fmaf(iD[3].z, xv.z, a3);    a3 = fmaf(iD[3].w, xv.w, a3);         \
        bool lo32 = (lane & 32) == 0;                                          \
        float tA = __shfl_xor(lo32 ? a2 : a0, 32);                             \
        float tB = __shfl_xor(lo32 ? a3 : a1, 32);                             \
        float rAq = (lo32 ? a0 : a2) + tA;                                     \
        float rBq = (lo32 ? a1 : a3) + tB;                                     \
        bool lo16 = (lane & 16) == 0;                                          \
        float tC = __shfl_xor(lo16 ? rBq : rAq, 16);                           \
        float r  = (lo16 ? rAq : rBq) + tC;                                    \
        r += __shfl_xor(r, 8);                                                 \
        r += __shfl_xor(r, 4);                                                 \
        r += __shfl_xor(r, 2);                                                 \
        r += __shfl_xor(r, 1);                                                 \
        if ((lane & 15) == 0)                                                  \
            zw[wave * 132 + (lane >> 4) * 33 + j] = r;                         \
    }

    for (int t = 0; t < tlimit; t++) {
        const int nbt = nbt_s[t];
        const int jmax = min(max(nbt - grp * 8, 0), 8);
        const int act = g_act && (t < mylen);
        const int pred_lo = (grp * 8 + rA < nbt);
        const int pred_hi = (grp * 8 + rA + 4 < nbt);

        // ---- prefetch x row (barrier-independent; consumed after staging) --
        int posx = dir ? ((t < xlen) ? xlen - 1 - t : t) : t;
        const float* xr = emb + (size_t)stok[xrow][posx] * EMB + xpart * 4;
        float4 xa = *(const float4*)xr;

        // ---- flag wait: wave0 only; lane l watches slice l's flag line ----
        if (t > 0 && wave == 0) {
            const unsigned tgt = (unsigned)t;
            const unsigned* cp = pollbase + lane * 16;
            bool mydone = false;
            while (true) {
                if (!mydone)
                    mydone = __hip_atomic_load(cp, __ATOMIC_RELAXED,
                                               __HIP_MEMORY_SCOPE_AGENT) >= tgt;
                if (__ballot(mydone) == ~0ull) break;
                __builtin_amdgcn_s_sleep(1);
            }
        }
        __syncthreads();

        // ---- stage h(t) = hbuf[..][t-1][..]; t==0 zero-fill (h(0)=0) ----
        {
            float4 u0 = {0.f, 0.f, 0.f, 0.f};
            float4 u1 = {0.f, 0.f, 0.f, 0.f};
            if (t > 0) {   // wave-uniform branch
                const char* baseD = hbase + (size_t)(t - 1) * HID * 4;
                const char* fb = baseD + o_fb;
                const char* a0 = pred_lo ? baseD + o_lo : fb;
                const char* a1 = pred_hi ? baseD + o_hi : fb;
                asm volatile(
                    "global_load_dwordx4 %0, %2, off sc0 sc1\n\t"
                    "global_load_dwordx4 %1, %3, off sc0 sc1\n\t"
                    "s_waitcnt vmcnt(0)"
                    : "=&v"(u0), "=&v"(u1)
                    : "v"(a0), "v"(a1)
                    : "memory");
            }
            *(float4*)&hs[(rA    ) * HSROW + wbBase] = u0;
            *(float4*)&hs[(rA + 4) * HSROW + wbBase] = u1;
            *(float4*)xdst = xa;
        }
        __syncthreads();

        // ---- dot: Whh.h + Wih.x fused (one dir) ----
        DOTRED();

        // ---- gates; SINGLE exchange+history store (agent scope) ----
        if (act) {
            float iv = zw[wave * 132 +  0 + gj] + bc[0];
            float fv = zw[wave * 132 + 33 + gj] + bc[1];
            float gv = zw[wave * 132 + 66 + gj] + bc[2];
            float ov = zw[wave * 132 + 99 + gj] + bc[3];
            float cn = sigmoidf_(fv) * cS + sigmoidf_(iv) * tanhf(gv);
            float hn = sigmoidf_(ov) * tanhf(cn);
            cS = cn;
            __hip_atomic_store(hout + (size_t)t * HID, hn,
                               __ATOMIC_RELAXED, __HIP_MEMORY_SCOPE_AGENT);
        }

        // ---- drain exchange stores, then single flag store (no RMW) ----
        __syncthreads();
        if (t < tlimit - 1 && tid == 0)
            __hip_atomic_store(myflag, (unsigned)(t + 1),
                               __ATOMIC_RELAXED, __HIP_MEMORY_SCOPE_AGENT);
    }
#undef DOTRED
}

// ---------------------------------------------------------------------------
// K3: feats — one wave per (b,t), all 64 lanes, LDS transpose-reduce.
// ---------------------------------------------------------------------------
__global__ __launch_bounds__(256) void k_feats(
    const int* __restrict__ lengths,
    const float* __restrict__ hbuf,  // [2][B][T][512]
    const float* __restrict__ Wout,  // [20][1024]
    const float* __restrict__ bout,  // [20]
    float* __restrict__ feats)       // [B][T][20]
{
    const int w = threadIdx.x >> 6;
    const int lane = threadIdx.x & 63;
    const int idx = blockIdx.x * 4 + w;
    const int b = idx >> 8, t = idx & 255;
    const int len = lengths[b];

    __shared__ float red[4][64][21];

    float acc[KTAGS];
    bool active = (t < len);
    if (active) {
        const int ofs = lane * 16;
        const float* src = (ofs < HID)
            ? hbuf + ((size_t)b * TT + t) * HID + ofs
            : hbuf + ((size_t)(BB + b) * TT + (len - 1 - t)) * HID + (ofs - HID);
        float x[16];
        #pragma unroll
        for (int q = 0; q < 4; q++) {
            float4 v = *(const float4*)(src + 4 * q);
            x[4 * q] = v.x; x[4 * q + 1] = v.y; x[4 * q + 2] = v.z; x[4 * q + 3] = v.w;
        }
        #pragma unroll
        for (int k = 0; k < KTAGS; k++) {
            const float* wr = Wout + (size_t)k * (2 * HID) + ofs;
            float a = 0.f;
            #pragma unroll
            for (int q = 0; q < 4; q++) {
                float4 v = *(const float4*)(wr + 4 * q);
                a = fmaf(x[4 * q], v.x, a);
                a = fmaf(x[4 * q + 1], v.y, a);
                a = fmaf(x[4 * q + 2], v.z, a);
                a = fmaf(x[4 * q + 3], v.w, a);
            }
            acc[k] = a;
        }
    } else {
        #pragma unroll
        for (int k = 0; k < KTAGS; k++) acc[k] = 0.f;
    }
    #pragma unroll
    for (int k = 0; k < KTAGS; k++) red[w][lane][k] = acc[k];
    __syncthreads();

    if (active && lane < KTAGS) {
        float s = bout[lane];
        #pragma unroll 8
        for (int l = 0; l < 64; l++) s += red[w][l][lane];
        feats[(size_t)idx * KTAGS + lane] = s;
    }
}

// ---------------------------------------------------------------------------
// K4: Viterbi — LDS backpointers, double-buffered fv, feats prefetch.
// ---------------------------------------------------------------------------
__global__ __launch_bounds__(64) void k_viterbi(
    const int* __restrict__ lengths,
    const float* __restrict__ trans,  // [20][20]
    const float* __restrict__ feats,  // [B][T][20]
    float* __restrict__ out)          // [32 scores][32*257 path]
{
    const int b = blockIdx.x;
    const int len = lengths[b];
    const int tid = threadIdx.x;

    __shared__ float tr[KTAGS * KTAGS];
    __shared__ float fvb[2][KTAGS];
    __shared__ int   bp[TT][KTAGS];
    __shared__ float term[KTAGS];

    for (int i = tid; i < KTAGS * KTAGS; i += 64) tr[i] = trans[i];
    if (tid < KTAGS) fvb[0][tid] = (tid == START_TAG) ? 0.f : NEGV;
    __syncthreads();

    float ft = (tid < KTAGS) ? feats[((size_t)b * TT) * KTAGS + tid] : 0.f;
    for (int t = 0; t < len; t++) {
        float ftn = (tid < KTAGS && t + 1 < len)
                  ? feats[((size_t)b * TT + t + 1) * KTAGS + tid] : 0.f;
        if (tid < KTAGS) {
            const float* fvc = fvb[t & 1];
            float best = -1e30f; int bi = 0;
            #pragma unroll
            for (int p = 0; p < KTAGS; p++) {
                float s = fvc[p] + tr[tid * KTAGS + p];
                if (s > best) { best = s; bi = p; }
            }
            fvb[(t + 1) & 1][tid] = best + ft;
            bp[t][tid] = bi;
        }
        ft = ftn;
        __syncthreads();
    }

    if (tid < KTAGS) term[tid] = fvb[len & 1][tid] + tr[END_TAG * KTAGS + tid];
    __syncthreads();

    if (tid == 0) {
        int bt_ = 0; float best = term[0];
        for (int k = 1; k < KTAGS; k++)
            if (term[k] > best) { best = term[k]; bt_ = k; }
        out[b] = best;
        float* path = out + BB + (size_t)b * (TT + 1);
        path[TT] = (float)bt_;
        int cur = bt_;
        for (int t = TT - 1; t >= 0; t--) {
            int src = t - (TT - len);
            if (src >= 0) cur = bp[src][cur];
            else          cur = KTAGS;
            path[t] = (float)cur;
        }
    }
}

// ---------------------------------------------------------------------------
extern "C" void kernel_launch(void* const* d_in, const int* in_sizes, int n_in,
                              void* d_out, int out_size, void* d_ws, size_t ws_size,
                              hipStream_t stream) {
    const int*   sentence = (const int*)d_in[0];
    const int*   lengths  = (const int*)d_in[1];
    const float* emb      = (const float*)d_in[2];
    const float* Wf_ih    = (const float*)d_in[3];
    const float* Wf_hh    = (const float*)d_in[4];
    const float* bf_ih    = (const float*)d_in[5];
    const float* bf_hh    = (const float*)d_in[6];
    const float* Wb_ih    = (const float*)d_in[7];
    const float* Wb_hh    = (const float*)d_in[8];
    const float* bb_ih    = (const float*)d_in[9];
    const float* bb_hh    = (const float*)d_in[10];
    const float* Wout     = (const float*)d_in[11];
    const float* bout     = (const float*)d_in[12];
    const float* trans    = (const float*)d_in[13];
    float* out = (float*)d_out;

    // workspace layout (hping slot retained for layout stability; unused)
    float*    hping = (float*)d_ws;                              // 256KB (unused)
    unsigned* flags = (unsigned*)((char*)d_ws + 262144);         // 32KB (512 x 64B lines)
    float*    hbuf  = (float*)((char*)d_ws + 262144 + 32768);    // 2*32*256*512 floats
    float*    feats = hbuf + (size_t)2 * BB * TT * HID;          // 32*256*20

    (void)hipMemsetAsync(d_ws, 0, 262144 + 32768, stream);

    hipLaunchKernelGGL(k_lstm_persist, dim3(512), dim3(512), 0, stream,
                       lengths, sentence, emb, Wf_hh, Wb_hh, Wf_ih, Wb_ih,
                       bf_ih, bf_hh, bb_ih, bb_hh, hping, flags, hbuf);
    hipLaunchKernelGGL(k_feats, dim3(BB * TT / 4), dim3(256), 0, stream,
                       lengths, hbuf, Wout, bout, feats);
    hipLaunchKernelGGL(k_viterbi, dim3(BB), dim3(64), 0, stream,
                       lengths, trans, feats, out);
}